// Round 6
// baseline (363.841 us; speedup 1.0000x reference)
//
#include <hip/hip_runtime.h>
#include <math.h>

// Problem constants
#define NVAR 3
#define BB 4
#define CC 256
#define C1 128
#define HEADS 4
#define HH 64
#define WW 64
#define HW 4096
#define RPE_W 127
#define NP 3
#define SCALE 0.17677669529663687f
// pairs: p=0 -> (i=1,j=0), p=1 -> (i=2,j=0), p=2 -> (i=2,j=1)

typedef short bf16x8 __attribute__((ext_vector_type(8)));
typedef float f32x4 __attribute__((ext_vector_type(4)));

__device__ __forceinline__ unsigned short f2bf(float f) {
    unsigned int u = __float_as_uint(f);
    u += 0x7fffu + ((u >> 16) & 1u);          // round-to-nearest-even
    return (unsigned short)(u >> 16);
}
__device__ __forceinline__ float bflo(unsigned u) { return __uint_as_float(u << 16); }
__device__ __forceinline__ float bfhi(unsigned u) { return __uint_as_float(u & 0xffff0000u); }

// ---------------------------------------------------------------------------
// 1) copy inputs -> output; SKIP channels 128:256 of vars 1,2 (conv_wo writes
//    those); zero the 12 flow elements.
__global__ __launch_bounds__(256) void copy_init(const float* __restrict__ x0,
                                                 const float* __restrict__ x1,
                                                 const float* __restrict__ x2,
                                                 float* __restrict__ out) {
    const long long per4 = (long long)BB * CC * HW / 4;   // float4 per var
    const long long tot4 = 3LL * per4;
    long long stride = (long long)gridDim.x * blockDim.x;
    for (long long i = (long long)blockIdx.x * blockDim.x + threadIdx.x;
         i < tot4 + 12; i += stride) {
        if (i < tot4) {
            int v = (int)(i / per4);
            long long r = i % per4;
            int chan = (int)((r >> 10) & 255);
            if (v > 0 && chan >= 128) continue;      // conv_wo owns these
            const float4* s = (v == 0) ? (const float4*)x0
                            : (v == 1) ? (const float4*)x1
                                       : (const float4*)x2;
            ((float4*)out)[i] = s[r];
        } else {
            out[3LL * BB * CC * HW + (i - tot4)] = 0.f;
        }
    }
}

// ---------------------------------------------------------------------------
// 1b) const prep: RPE table -> bf16 [ph][128][128] (edges zeroed);
//     Wq -> bf16 hi+lo; Wo -> bf16 hi.
__global__ __launch_bounds__(256) void prep_const(const float* __restrict__ rpe,
                                                  const float* __restrict__ Wq,
                                                  const float* __restrict__ Wo,
                                                  unsigned short* __restrict__ tabbf,
                                                  unsigned short* __restrict__ wqh,
                                                  unsigned short* __restrict__ wql,
                                                  unsigned short* __restrict__ woh) {
    int blk = blockIdx.x;
    if (blk < 12) {
        const float* src = rpe + (long long)blk * RPE_W * RPE_W;
        unsigned short* dst = tabbf + (long long)blk * 16384;
        for (int idx = threadIdx.x; idx < 16384; idx += 256) {
            int y = idx >> 7, x = idx & 127;
            float v = (y < RPE_W && x < RPE_W) ? src[y * RPE_W + x] : 0.f;
            dst[idx] = f2bf(v);
        }
    } else if (blk < 15) {
        int p = blk - 12;
        for (int i = threadIdx.x; i < 16384; i += 256) {
            float w = Wq[p * 16384 + i];
            unsigned short h = f2bf(w);
            wqh[p * 16384 + i] = h;
            wql[p * 16384 + i] = f2bf(w - bflo((unsigned)h));
        }
    } else {
        int p = blk - 15;
        for (int i = threadIdx.x; i < 16384; i += 256)
            woh[p * 16384 + i] = f2bf(Wo[p * 16384 + i]);
    }
}

// ---------------------------------------------------------------------------
// 2) conv_q via MFMA, split bf16 (hi+lo) for ~fp32 accuracy.
//    Wave computes [128 c] x [16 m]. Outputs qbuf f32 [pb][c][m] and
//    qbf bf16 [pb][m][c] (pre-scaled).
__global__ __launch_bounds__(256) void conv_q(const float* __restrict__ x1,
                                              const float* __restrict__ x2,
                                              const unsigned short* __restrict__ wqh,
                                              const unsigned short* __restrict__ wql,
                                              const float* __restrict__ bq,
                                              float* __restrict__ qbuf,
                                              unsigned short* __restrict__ qbf) {
    int wid = threadIdx.x >> 6, lane = threadIdx.x & 63;
    int g = lane >> 4, lm = lane & 15;
    int gw = blockIdx.x * 4 + wid;            // 3072 waves
    int mt = gw & 255;
    int pb = gw >> 8;
    int p = pb >> 2, b = pb & 3;
    const float* X = ((p == 0) ? x1 : x2) + (long long)b * CC * HW;
    int m = mt * 16 + lm;

    // B fragments: x column m, k = 0..127, split hi/lo
    bf16x8 bhi[4], blo[4];
#pragma unroll
    for (int ksl = 0; ksl < 4; ksl++) {
        float v[8];
#pragma unroll
        for (int j = 0; j < 8; j++)
            v[j] = X[(long long)(ksl * 32 + 8 * g + j) * HW + m];
        union { unsigned u[4]; bf16x8 v; } H, L;
#pragma unroll
        for (int t = 0; t < 4; t++) {
            unsigned short h0 = f2bf(v[2 * t]), h1 = f2bf(v[2 * t + 1]);
            unsigned short l0 = f2bf(v[2 * t] - bflo((unsigned)h0));
            unsigned short l1 = f2bf(v[2 * t + 1] - bflo((unsigned)h1));
            H.u[t] = (unsigned)h0 | ((unsigned)h1 << 16);
            L.u[t] = (unsigned)l0 | ((unsigned)l1 << 16);
        }
        bhi[ksl] = H.v;
        blo[ksl] = L.v;
    }

    const unsigned short* WH = wqh + p * 16384;
    const unsigned short* WL = wql + p * 16384;
    f32x4 zero = {0.f, 0.f, 0.f, 0.f};
#pragma unroll
    for (int ct2 = 0; ct2 < 4; ct2++) {
        int ct0 = 2 * ct2, ct1 = ct0 + 1;
        f32x4 a0 = zero, a1 = zero;
#pragma unroll
        for (int ksl = 0; ksl < 4; ksl++) {
            bf16x8 Ah0 = *(const bf16x8*)(WH + (ct0 * 16 + lm) * 128 + ksl * 32 + 8 * g);
            bf16x8 Al0 = *(const bf16x8*)(WL + (ct0 * 16 + lm) * 128 + ksl * 32 + 8 * g);
            bf16x8 Ah1 = *(const bf16x8*)(WH + (ct1 * 16 + lm) * 128 + ksl * 32 + 8 * g);
            bf16x8 Al1 = *(const bf16x8*)(WL + (ct1 * 16 + lm) * 128 + ksl * 32 + 8 * g);
            a0 = __builtin_amdgcn_mfma_f32_16x16x32_bf16(Ah0, bhi[ksl], a0, 0, 0, 0);
            a1 = __builtin_amdgcn_mfma_f32_16x16x32_bf16(Ah1, bhi[ksl], a1, 0, 0, 0);
            a0 = __builtin_amdgcn_mfma_f32_16x16x32_bf16(Ah0, blo[ksl], a0, 0, 0, 0);
            a1 = __builtin_amdgcn_mfma_f32_16x16x32_bf16(Ah1, blo[ksl], a1, 0, 0, 0);
            a0 = __builtin_amdgcn_mfma_f32_16x16x32_bf16(Al0, bhi[ksl], a0, 0, 0, 0);
            a1 = __builtin_amdgcn_mfma_f32_16x16x32_bf16(Al1, bhi[ksl], a1, 0, 0, 0);
        }
        float q0[4], q1[4];
#pragma unroll
        for (int r = 0; r < 4; r++) {
            int c0 = ct0 * 16 + 4 * g + r, c1 = ct1 * 16 + 4 * g + r;
            q0[r] = a0[r] + bq[p * 128 + c0];
            q1[r] = a1[r] + bq[p * 128 + c1];
            qbuf[((long long)pb * 128 + c0) * HW + m] = q0[r];
            qbuf[((long long)pb * 128 + c1) * HW + m] = q1[r];
        }
        unsigned short* Yb = qbf + ((long long)pb * HW + m) * 128;
        *(unsigned*)(Yb + ct0 * 16 + 4 * g) =
            (unsigned)f2bf(q0[0] * SCALE) | ((unsigned)f2bf(q0[1] * SCALE) << 16);
        *(unsigned*)(Yb + ct0 * 16 + 4 * g + 2) =
            (unsigned)f2bf(q0[2] * SCALE) | ((unsigned)f2bf(q0[3] * SCALE) << 16);
        *(unsigned*)(Yb + ct1 * 16 + 4 * g) =
            (unsigned)f2bf(q1[0] * SCALE) | ((unsigned)f2bf(q1[1] * SCALE) << 16);
        *(unsigned*)(Yb + ct1 * 16 + 4 * g + 2) =
            (unsigned)f2bf(q1[2] * SCALE) | ((unsigned)f2bf(q1[3] * SCALE) << 16);
    }
}

// ---------------------------------------------------------------------------
// 3) offset net, one wave per (p,b,s): depthwise 4x4 -> LN -> GELU -> 1x1;
//    shfl-only reductions, also emits the attn bias params (prm).
__global__ __launch_bounds__(64) void offset_net(const float* __restrict__ qbuf,
                                                 const float* __restrict__ dw_w,
                                                 const float* __restrict__ dw_b,
                                                 const float* __restrict__ ln_g,
                                                 const float* __restrict__ ln_b,
                                                 const float* __restrict__ pw_w,
                                                 float* __restrict__ posb,
                                                 uint4* __restrict__ prmb) {
    int blk = blockIdx.x;               // p*1024 + b*256 + s
    int p = blk >> 10;
    int r = blk & 1023;
    int b = r >> 8;
    int s = r & 255;
    int hk = s >> 4, wk = s & 15;
    int lane = threadIdx.x;

    float a[2];
#pragma unroll
    for (int half = 0; half < 2; half++) {
        int c = lane + 64 * half;
        const float* qp = qbuf + (((long long)(p * 4 + b)) * 128 + c) * HW
                          + (hk * 4) * WW + wk * 4;
        const float* dwp = dw_w + (p * 128 + c) * 16;
        float acc = dw_b[p * 128 + c];
#pragma unroll
        for (int ky = 0; ky < 4; ky++)
#pragma unroll
            for (int kx = 0; kx < 4; kx++)
                acc += qp[ky * WW + kx] * dwp[ky * 4 + kx];
        a[half] = acc;
    }
    float s1 = a[0] + a[1];
#pragma unroll
    for (int off = 1; off < 64; off <<= 1) s1 += __shfl_xor(s1, off);
    float mu = s1 * (1.f / 128.f);
    float d0 = a[0] - mu, d1 = a[1] - mu;
    float v2 = d0 * d0 + d1 * d1;
#pragma unroll
    for (int off = 1; off < 64; off <<= 1) v2 += __shfl_xor(v2, off);
    float rs = rsqrtf(v2 * (1.f / 128.f) + 1e-5f);
    int c0 = lane, c1 = lane + 64;
    float y0 = d0 * rs * ln_g[p * 128 + c0] + ln_b[p * 128 + c0];
    float y1 = d1 * rs * ln_g[p * 128 + c1] + ln_b[p * 128 + c1];
    float g0 = 0.5f * y0 * (1.f + erff(y0 * 0.70710678118654752f));
    float g1 = 0.5f * y1 * (1.f + erff(y1 * 0.70710678118654752f));
    float o0 = pw_w[(p * 2 + 0) * 128 + c0] * g0 + pw_w[(p * 2 + 0) * 128 + c1] * g1;
    float o1 = pw_w[(p * 2 + 1) * 128 + c0] * g0 + pw_w[(p * 2 + 1) * 128 + c1] * g1;
#pragma unroll
    for (int off = 1; off < 64; off <<= 1) o0 += __shfl_xor(o0, off);
#pragma unroll
    for (int off = 1; off < 64; off <<= 1) o1 += __shfl_xor(o1, off);
    if (lane == 0) {
        float refy = (hk + 0.5f) * (2.f / 15.f) - 1.f;
        float refx = (wk + 0.5f) * (2.f / 15.f) - 1.f;
        float py = fminf(fmaxf(o0 + refy, -1.f), 1.f);
        float px = fminf(fmaxf(o1 + refx, -1.f), 1.f);
        int pbn = (p * 4 + b) * 256 + s;
        posb[pbn * 2 + 0] = py;
        posb[pbn * 2 + 1] = px;
        // attn bias params
        float cy = 31.5f * (1.f - py), cx = 31.5f * (1.f - px);
        float yf = floorf(cy), xf = floorf(cx);
        float wy = cy - yf, wx = cx - xf;
        int Y0 = (int)yf, X0 = (int)xf;
        uint4 v;
        v.x = (unsigned)f2bf((1.f - wy) * (1.f - wx))
            | ((unsigned)f2bf((1.f - wy) * wx) << 16);
        v.y = (unsigned)f2bf(wy * (1.f - wx))
            | ((unsigned)f2bf(wy * wx) << 16);
        v.z = (unsigned)((Y0 * 128 + X0) * 2);
        v.w = 0;
        prmb[pbn] = v;
    }
}

// ---------------------------------------------------------------------------
// 4) bilinear sample kv at pos -> xsb [p][b][128][256]
__global__ __launch_bounds__(128) void sample_xs(const float* __restrict__ x0,
                                                 const float* __restrict__ x1,
                                                 const float* __restrict__ posb,
                                                 float* __restrict__ xsb) {
    int blk = blockIdx.x;
    int p = blk >> 10;
    int r = blk & 1023;
    int b = r >> 8;
    int s = r & 255;
    const float* kv = ((p == 2) ? x1 : x0) + (long long)b * CC * HW;
    float gy = posb[((p * 4 + b) * 256 + s) * 2 + 0];
    float gx = posb[((p * 4 + b) * 256 + s) * 2 + 1];
    float xi = (gx + 1.f) * 31.5f;
    float yi = (gy + 1.f) * 31.5f;
    float xf = floorf(xi), yf = floorf(yi);
    int xI = (int)xf, yI = (int)yf;
    float wx = xi - xf, wy = yi - yf;
    int c = threadIdx.x;
    const float* img = kv + (long long)c * HW;
    float v00 = 0.f, v01 = 0.f, v10 = 0.f, v11 = 0.f;
    bool y0ok = (yI >= 0) && (yI < HH);
    bool y1ok = (yI + 1 >= 0) && (yI + 1 < HH);
    bool x0ok = (xI >= 0) && (xI < WW);
    bool x1ok = (xI + 1 >= 0) && (xI + 1 < WW);
    int yc0 = min(max(yI, 0), HH - 1), yc1 = min(max(yI + 1, 0), HH - 1);
    int xc0 = min(max(xI, 0), WW - 1), xc1 = min(max(xI + 1, 0), WW - 1);
    if (y0ok && x0ok) v00 = img[yc0 * WW + xc0];
    if (y0ok && x1ok) v01 = img[yc0 * WW + xc1];
    if (y1ok && x0ok) v10 = img[yc1 * WW + xc0];
    if (y1ok && x1ok) v11 = img[yc1 * WW + xc1];
    float val = (1.f - wy) * ((1.f - wx) * v00 + wx * v01)
              + wy * ((1.f - wx) * v10 + wx * v11);
    xsb[(((long long)(p * 4 + b)) * 128 + c) * 256 + s] = val;
}

// ---------------------------------------------------------------------------
// 5) k AND v = W @ xs + b, bf16 outputs:
//    kbf [pb][n(256)][c(128)]  (c contiguous)
//    vbf [pb][c(128)][n(256)]  (n contiguous)
__global__ __launch_bounds__(256) void conv_kv(const float* __restrict__ X,
                                               const float* __restrict__ Wk,
                                               const float* __restrict__ bk,
                                               const float* __restrict__ Wv,
                                               const float* __restrict__ bv,
                                               unsigned short* __restrict__ kbf,
                                               unsigned short* __restrict__ vbf) {
    int blk = blockIdx.x;                 // NP*BB*8
    int pb = blk >> 3;
    int tile = blk & 7;
    int p = pb >> 2;
    int m0 = tile * 32;
    const float* Xb = X + (long long)pb * 128 * 256;
    __shared__ float4 xt4[128][8];
    for (int idx = threadIdx.x; idx < 1024; idx += 256) {
        int cc = idx >> 3, i8 = idx & 7;
        xt4[cc][i8] = *(const float4*)(Xb + cc * 256 + m0 + i8 * 4);
    }
    __syncthreads();
    int c = threadIdx.x & 127;
    bool isv = threadIdx.x >= 128;
    const float* W = isv ? Wv : Wk;
    const float* bias = isv ? bv : bk;
    const float4* Wrow = (const float4*)(W + (p * 128 + c) * 128);
    float4 a4[8];
#pragma unroll
    for (int i = 0; i < 8; i++) a4[i] = make_float4(0.f, 0.f, 0.f, 0.f);
    for (int cp4 = 0; cp4 < 32; cp4++) {
        float4 w = Wrow[cp4];
#pragma unroll
        for (int k = 0; k < 4; k++) {
            float wv = (k == 0) ? w.x : (k == 1) ? w.y : (k == 2) ? w.z : w.w;
#pragma unroll
            for (int i = 0; i < 8; i++) {
                float4 xv = xt4[cp4 * 4 + k][i];
                a4[i].x += wv * xv.x; a4[i].y += wv * xv.y;
                a4[i].z += wv * xv.z; a4[i].w += wv * xv.w;
            }
        }
    }
    float bvv = bias[p * 128 + c];
    float acc[32];
#pragma unroll
    for (int i = 0; i < 8; i++) {
        acc[i * 4 + 0] = a4[i].x + bvv; acc[i * 4 + 1] = a4[i].y + bvv;
        acc[i * 4 + 2] = a4[i].z + bvv; acc[i * 4 + 3] = a4[i].w + bvv;
    }
    if (!isv) {
        unsigned short* Yp = kbf + ((long long)pb * 256 + m0) * 128 + c;
#pragma unroll
        for (int i = 0; i < 32; i++) Yp[i * 128] = f2bf(acc[i]);
    } else {
        unsigned short* Yp = vbf + ((long long)pb * 128 + c) * 256 + m0;
#pragma unroll
        for (int k = 0; k < 16; k++) {
            unsigned int pk = (unsigned int)f2bf(acc[2 * k])
                            | ((unsigned int)f2bf(acc[2 * k + 1]) << 16);
            *(unsigned int*)(Yp + 2 * k) = pk;
        }
    }
}

// ---------------------------------------------------------------------------
// 6) MFMA attention v3: 512-thread blocks (8 waves, 2 query rows) share one
//    32KB RPE table -> 4 blocks/CU = 32 waves/CU. Otherwise as R5.
__global__ __launch_bounds__(512, 8) void attn_mfma(
        const unsigned short* __restrict__ qbf,
        const unsigned short* __restrict__ kbf,
        const unsigned short* __restrict__ vbf,
        const unsigned short* __restrict__ tabbf,
        const uint4* __restrict__ prmb,
        float* __restrict__ obuf) {
    __shared__ unsigned short tab[16384];     // 32 KB
    __shared__ uint4 prm[256];                // 4 KB
    int tid = threadIdx.x;
    int wid = tid >> 6, lane = tid & 63;
    int g = lane >> 4, lm = lane & 15;
    int bid = blockIdx.x;                     // 1536
    int my = ((bid & 31) << 1) + (wid >> 2);
    int h = (bid >> 5) & 3;
    int b = (bid >> 7) & 3;
    int p = bid >> 9;
    int pb = p * 4 + b;

    {   // stage table + params
        const uint4* ts = (const uint4*)(tabbf + (long long)(p * 4 + h) * 16384);
        uint4* td = (uint4*)tab;
#pragma unroll
        for (int i = 0; i < 4; i++) td[tid + i * 512] = ts[tid + i * 512];
        if (tid < 256) prm[tid] = prmb[pb * 256 + tid];
    }
    __syncthreads();

    int mx = ((wid & 3) << 4) + lm;

    // ---- QK^T (swapped): A = K[n][c], B = Q^T[c][m]; q pre-scaled ----
    bf16x8 qf = *(const bf16x8*)(qbf + ((long long)pb * HW + my * 64 + mx) * 128
                                 + h * 32 + 8 * g);
    const unsigned short* kbase = kbf + ((long long)pb * 256 + lm) * 128
                                  + h * 32 + 8 * g;
    f32x4 zero = {0.f, 0.f, 0.f, 0.f};
    f32x4 acc[16];
#pragma unroll
    for (int ni = 0; ni < 16; ni++) {
        bf16x8 kf = *(const bf16x8*)(kbase + ni * 16 * 128);
        acc[ni] = __builtin_amdgcn_mfma_f32_16x16x32_bf16(kf, qf, zero, 0, 0, 0);
    }

    // ---- RPE bias from LDS table: 4x ds_read_u16 + 4 FMA per logit ----
    int laneoff = (my * 128 + mx) * 2;
    const char* tb = (const char*)tab;
#pragma unroll
    for (int ni = 0; ni < 16; ni++) {
#pragma unroll
        for (int r = 0; r < 4; r++) {
            int n = ni * 16 + 4 * g + r;
            uint4 pw = prm[n];
            int va = (int)pw.z + laneoff;
            float a0 = bflo(*(const unsigned short*)(tb + va));
            float a1 = bflo(*(const unsigned short*)(tb + va + 2));
            float b0 = bflo(*(const unsigned short*)(tb + va + 256));
            float b1 = bflo(*(const unsigned short*)(tb + va + 258));
            float t = fmaf(bflo(pw.x), a0, acc[ni][r]);
            t = fmaf(bfhi(pw.x), a1, t);
            t = fmaf(bflo(pw.y), b0, t);
            t = fmaf(bfhi(pw.y), b1, t);
            acc[ni][r] = t;
        }
    }

    // ---- softmax over n (in-register + shfl_xor over g-groups) ----
    float mxv = -1e30f;
#pragma unroll
    for (int ni = 0; ni < 16; ni++)
        mxv = fmaxf(mxv, fmaxf(fmaxf(acc[ni][0], acc[ni][1]),
                               fmaxf(acc[ni][2], acc[ni][3])));
    mxv = fmaxf(mxv, __shfl_xor(mxv, 16));
    mxv = fmaxf(mxv, __shfl_xor(mxv, 32));
    float sum = 0.f;
    unsigned dwA[16], dwB[16];
#pragma unroll
    for (int ni = 0; ni < 16; ni++) {
        float e0 = __expf(acc[ni][0] - mxv);
        float e1 = __expf(acc[ni][1] - mxv);
        float e2 = __expf(acc[ni][2] - mxv);
        float e3 = __expf(acc[ni][3] - mxv);
        sum += (e0 + e1) + (e2 + e3);
        asm("v_cvt_pk_bf16_f32 %0, %1, %2" : "=v"(dwA[ni]) : "v"(e0), "v"(e1));
        asm("v_cvt_pk_bf16_f32 %0, %1, %2" : "=v"(dwB[ni]) : "v"(e2), "v"(e3));
    }
    sum += __shfl_xor(sum, 16);
    sum += __shfl_xor(sum, 32);

    // ---- PV: pf = P^T[32st+8g+j][lm] assembled via shfl exchange ----
    int src0 = ((g & 1) << 5) + lm;
    int src1 = src0 + 16;
    bool sel = (g >> 1) != 0;
    const unsigned short* vb0 = vbf + ((long long)pb * 128 + h * 32 + lm) * 256
                                + 8 * g;
    f32x4 o0 = zero, o1 = zero;
#pragma unroll
    for (int st = 0; st < 8; st++) {
        unsigned d0a = __shfl(dwA[2 * st], src0), d0b = __shfl(dwA[2 * st + 1], src0);
        unsigned d1a = __shfl(dwB[2 * st], src0), d1b = __shfl(dwB[2 * st + 1], src0);
        unsigned d2a = __shfl(dwA[2 * st], src1), d2b = __shfl(dwA[2 * st + 1], src1);
        unsigned d3a = __shfl(dwB[2 * st], src1), d3b = __shfl(dwB[2 * st + 1], src1);
        union { unsigned u[4]; bf16x8 v; } pf;
        pf.u[0] = sel ? d0b : d0a;
        pf.u[1] = sel ? d1b : d1a;
        pf.u[2] = sel ? d2b : d2a;
        pf.u[3] = sel ? d3b : d3a;
        bf16x8 v0 = *(const bf16x8*)(vb0 + st * 32);
        bf16x8 v1 = *(const bf16x8*)(vb0 + 4096 + st * 32);
        o0 = __builtin_amdgcn_mfma_f32_16x16x32_bf16(v0, pf.v, o0, 0, 0, 0);
        o1 = __builtin_amdgcn_mfma_f32_16x16x32_bf16(v1, pf.v, o1, 0, 0, 0);
    }

    float inv = 1.f / sum;
    float* ob = obuf + ((long long)pb * 128 + h * 32) * HW + my * 64 + mx;
#pragma unroll
    for (int r = 0; r < 4; r++) {
        ob[(g * 4 + r) * HW] = o0[r] * inv;
        ob[(16 + g * 4 + r) * HW] = o1[r] * inv;
    }
}

// ---------------------------------------------------------------------------
// 7) conv_wo via MFMA (bf16 hi): writes out = x + sum_p Wo[p] o[p] + bo on
//    channels 128:256 of vars 1,2. Wave = [128 c_out] x [16 m].
__global__ __launch_bounds__(256) void conv_wo(const float* __restrict__ x1,
                                               const float* __restrict__ x2,
                                               const float* __restrict__ obuf,
                                               const unsigned short* __restrict__ woh,
                                               const float* __restrict__ bo,
                                               float* __restrict__ out) {
    int wid = threadIdx.x >> 6, lane = threadIdx.x & 63;
    int g = lane >> 4, lm = lane & 15;
    int gw = blockIdx.x * 4 + wid;            // 2048 waves
    int mt = gw & 255;
    int b = (gw >> 8) & 3;
    int vs = gw >> 10;                        // 0 -> var1, 1 -> var2
    int m = mt * 16 + lm;
    int np = vs + 1;

    f32x4 acc[8];
#pragma unroll
    for (int ct = 0; ct < 8; ct++) acc[ct] = (f32x4){0.f, 0.f, 0.f, 0.f};

    for (int pi = 0; pi < np; pi++) {
        int p = vs ? (1 + pi) : 0;
        const float* O = obuf + (long long)(p * 4 + b) * 128 * HW;
        bf16x8 bh[4];
#pragma unroll
        for (int ksl = 0; ksl < 4; ksl++) {
            float v[8];
#pragma unroll
            for (int j = 0; j < 8; j++)
                v[j] = O[(long long)(ksl * 32 + 8 * g + j) * HW + m];
            union { unsigned u[4]; bf16x8 v; } H;
#pragma unroll
            for (int t = 0; t < 4; t++)
                H.u[t] = (unsigned)f2bf(v[2 * t]) | ((unsigned)f2bf(v[2 * t + 1]) << 16);
            bh[ksl] = H.v;
        }
        const unsigned short* WH = woh + p * 16384;
#pragma unroll
        for (int ct = 0; ct < 8; ct++)
#pragma unroll
            for (int ksl = 0; ksl < 4; ksl++) {
                bf16x8 A = *(const bf16x8*)(WH + (ct * 16 + lm) * 128 + ksl * 32 + 8 * g);
                acc[ct] = __builtin_amdgcn_mfma_f32_16x16x32_bf16(A, bh[ksl], acc[ct], 0, 0, 0);
            }
    }

    int qi = vs + 1;
    const float* xq = (vs ? x2 : x1) + (long long)b * CC * HW;
#pragma unroll
    for (int ct = 0; ct < 8; ct++)
#pragma unroll
        for (int r = 0; r < 4; r++) {
            int c = ct * 16 + 4 * g + r;
            float bias = vs ? (bo[128 + c] + bo[256 + c]) : bo[c];
            float base = xq[(long long)(128 + c) * HW + m];
            out[(((long long)(qi * 4 + b)) * CC + 128 + c) * HW + m]
                = base + acc[ct][r] + bias;
        }
}

// ---------------------------------------------------------------------------
extern "C" void kernel_launch(void* const* d_in, const int* in_sizes, int n_in,
                              void* d_out, int out_size, void* d_ws, size_t ws_size,
                              hipStream_t stream) {
    const float* x0 = (const float*)d_in[0];
    const float* x1 = (const float*)d_in[1];
    const float* x2 = (const float*)d_in[2];
    const float* Wq = (const float*)d_in[3];
    const float* bq = (const float*)d_in[4];
    const float* Wk = (const float*)d_in[5];
    const float* bk = (const float*)d_in[6];
    const float* Wv = (const float*)d_in[7];
    const float* bv = (const float*)d_in[8];
    const float* Wo = (const float*)d_in[9];
    const float* bo = (const float*)d_in[10];
    const float* dw_w = (const float*)d_in[11];
    const float* dw_b = (const float*)d_in[12];
    const float* ln_g = (const float*)d_in[13];
    const float* ln_b = (const float*)d_in[14];
    const float* pw_w = (const float*)d_in[15];
    const float* rpe = (const float*)d_in[16];
    float* out = (float*)d_out;

    // workspace layout. obuf aliases qbuf (disjoint lifetimes).
    float* ws = (float*)d_ws;
    float* qbuf = ws;                                   // 6291456 f
    float* obuf = qbuf;                                 // alias
    float* posb = ws + 6291456;                         // 6144 f
    float* xsb  = posb + 6144;                          // 393216 f
    unsigned short* qbf = (unsigned short*)(xsb + 393216);   // 12582912 s
    unsigned short* kbf = qbf + 12582912;                    // 393216 s
    unsigned short* vbf = kbf + 393216;                      // 393216 s
    unsigned short* tabbf = vbf + 393216;                    // 196608 s
    uint4* prmb = (uint4*)(tabbf + 196608);                  // 3072 uint4
    unsigned short* wqh = (unsigned short*)(prmb + 3072);    // 49152 s
    unsigned short* wql = wqh + 49152;                       // 49152 s
    unsigned short* woh = wql + 49152;                       // 49152 s

    copy_init<<<2048, 256, 0, stream>>>(x0, x1, x2, out);
    prep_const<<<18, 256, 0, stream>>>(rpe, Wq, Wo, tabbf, wqh, wql, woh);
    conv_q<<<768, 256, 0, stream>>>(x1, x2, wqh, wql, bq, qbuf, qbf);
    offset_net<<<NP * BB * 256, 64, 0, stream>>>(qbuf, dw_w, dw_b, ln_g, ln_b,
                                                 pw_w, posb, prmb);
    sample_xs<<<NP * BB * 256, 128, 0, stream>>>(x0, x1, posb, xsb);
    conv_kv<<<NP * BB * 8, 256, 0, stream>>>(xsb, Wk, bk, Wv, bv, kbf, vbf);
    attn_mfma<<<1536, 512, 0, stream>>>(qbf, kbf, vbf, tabbf, prmb, obuf);
    conv_wo<<<512, 256, 0, stream>>>(x1, x2, obuf, woh, bo, out);
}

// Round 8
// 188.647 us; speedup vs baseline: 1.9287x; 1.9287x over previous
//
#include <hip/hip_runtime.h>
#include <math.h>

// Problem constants
#define NVAR 3
#define BB 4
#define CC 256
#define C1 128
#define HEADS 4
#define HH 64
#define WW 64
#define HW 4096
#define RPE_W 127
#define NP 3
#define SCALE 0.17677669529663687f
// pairs: p=0 -> (i=1,j=0), p=1 -> (i=2,j=0), p=2 -> (i=2,j=1)

typedef short bf16x8 __attribute__((ext_vector_type(8)));
typedef float f32x4 __attribute__((ext_vector_type(4)));

__device__ __forceinline__ unsigned short f2bf(float f) {
    unsigned int u = __float_as_uint(f);
    u += 0x7fffu + ((u >> 16) & 1u);          // round-to-nearest-even
    return (unsigned short)(u >> 16);
}
__device__ __forceinline__ float bflo(unsigned u) { return __uint_as_float(u << 16); }
__device__ __forceinline__ float bfhi(unsigned u) { return __uint_as_float(u & 0xffff0000u); }

// ---------------------------------------------------------------------------
// 1) copy x0 -> out var0; zero the 12 flow elements. (vars 1,2 chans 0:128
//    written by conv_q; chans 128:256 by conv_wo.)
__global__ __launch_bounds__(256) void copy_init(const float* __restrict__ x0,
                                                 float* __restrict__ out) {
    const long long n4 = (long long)BB * CC * HW / 4;
    long long stride = (long long)gridDim.x * blockDim.x;
    for (long long i = (long long)blockIdx.x * blockDim.x + threadIdx.x;
         i < n4 + 12; i += stride) {
        if (i < n4) ((float4*)out)[i] = ((const float4*)x0)[i];
        else out[3LL * BB * CC * HW + (i - n4)] = 0.f;
    }
}

// ---------------------------------------------------------------------------
// 1b) const prep: RPE -> bf16 [ph][128][128] (edges zeroed); Wq hi+lo;
//     Wo, Wk, Wv -> bf16.
__global__ __launch_bounds__(256) void prep_const(const float* __restrict__ rpe,
                                                  const float* __restrict__ Wq,
                                                  const float* __restrict__ Wo,
                                                  const float* __restrict__ Wk,
                                                  const float* __restrict__ Wv,
                                                  unsigned short* __restrict__ tabbf,
                                                  unsigned short* __restrict__ wqh,
                                                  unsigned short* __restrict__ wql,
                                                  unsigned short* __restrict__ woh,
                                                  unsigned short* __restrict__ wkh,
                                                  unsigned short* __restrict__ wvh) {
    int blk = blockIdx.x;
    if (blk < 12) {
        const float* src = rpe + (long long)blk * RPE_W * RPE_W;
        unsigned short* dst = tabbf + (long long)blk * 16384;
        for (int idx = threadIdx.x; idx < 16384; idx += 256) {
            int y = idx >> 7, x = idx & 127;
            float v = (y < RPE_W && x < RPE_W) ? src[y * RPE_W + x] : 0.f;
            dst[idx] = f2bf(v);
        }
    } else if (blk < 15) {
        int p = blk - 12;
        for (int i = threadIdx.x; i < 16384; i += 256) {
            float w = Wq[p * 16384 + i];
            unsigned short h = f2bf(w);
            wqh[p * 16384 + i] = h;
            wql[p * 16384 + i] = f2bf(w - bflo((unsigned)h));
        }
    } else if (blk < 18) {
        int p = blk - 15;
        for (int i = threadIdx.x; i < 16384; i += 256)
            woh[p * 16384 + i] = f2bf(Wo[p * 16384 + i]);
    } else if (blk < 21) {
        int p = blk - 18;
        for (int i = threadIdx.x; i < 16384; i += 256)
            wkh[p * 16384 + i] = f2bf(Wk[p * 16384 + i]);
    } else {
        int p = blk - 21;
        for (int i = threadIdx.x; i < 16384; i += 256)
            wvh[p * 16384 + i] = f2bf(Wv[p * 16384 + i]);
    }
}

// ---------------------------------------------------------------------------
// 2) conv_q via MFMA, split bf16 (hi+lo). Outputs qbuf f32 [pb][c][m],
//    qbf bf16 [pb][m][c] (pre-scaled), AND copies x chans 0:128 into out
//    (p=0 -> var1, p=1 -> var2; p=2 duplicate skipped).
__global__ __launch_bounds__(256) void conv_q(const float* __restrict__ x1,
                                              const float* __restrict__ x2,
                                              const unsigned short* __restrict__ wqh,
                                              const unsigned short* __restrict__ wql,
                                              const float* __restrict__ bq,
                                              float* __restrict__ qbuf,
                                              unsigned short* __restrict__ qbf,
                                              float* __restrict__ out) {
    int wid = threadIdx.x >> 6, lane = threadIdx.x & 63;
    int g = lane >> 4, lm = lane & 15;
    int gw = blockIdx.x * 4 + wid;            // 3072 waves
    int mt = gw & 255;
    int pb = gw >> 8;
    int p = pb >> 2, b = pb & 3;
    const float* X = ((p == 0) ? x1 : x2) + (long long)b * CC * HW;
    int m = mt * 16 + lm;
    float* outc = (p < 2)
        ? out + (((long long)((p + 1) * 4 + b)) * CC) * HW + m
        : nullptr;

    // B fragments: x column m, k = 0..127, split hi/lo; also copy to out.
    bf16x8 bhi[4], blo[4];
#pragma unroll
    for (int ksl = 0; ksl < 4; ksl++) {
        float v[8];
#pragma unroll
        for (int j = 0; j < 8; j++) {
            int k = ksl * 32 + 8 * g + j;
            v[j] = X[(long long)k * HW + m];
            if (outc) outc[(long long)k * HW] = v[j];
        }
        union { unsigned u[4]; bf16x8 v; } H, L;
#pragma unroll
        for (int t = 0; t < 4; t++) {
            unsigned short h0 = f2bf(v[2 * t]), h1 = f2bf(v[2 * t + 1]);
            unsigned short l0 = f2bf(v[2 * t] - bflo((unsigned)h0));
            unsigned short l1 = f2bf(v[2 * t + 1] - bflo((unsigned)h1));
            H.u[t] = (unsigned)h0 | ((unsigned)h1 << 16);
            L.u[t] = (unsigned)l0 | ((unsigned)l1 << 16);
        }
        bhi[ksl] = H.v;
        blo[ksl] = L.v;
    }

    const unsigned short* WH = wqh + p * 16384;
    const unsigned short* WL = wql + p * 16384;
    f32x4 zero = {0.f, 0.f, 0.f, 0.f};
#pragma unroll
    for (int ct2 = 0; ct2 < 4; ct2++) {
        int ct0 = 2 * ct2, ct1 = ct0 + 1;
        f32x4 a0 = zero, a1 = zero;
#pragma unroll
        for (int ksl = 0; ksl < 4; ksl++) {
            bf16x8 Ah0 = *(const bf16x8*)(WH + (ct0 * 16 + lm) * 128 + ksl * 32 + 8 * g);
            bf16x8 Al0 = *(const bf16x8*)(WL + (ct0 * 16 + lm) * 128 + ksl * 32 + 8 * g);
            bf16x8 Ah1 = *(const bf16x8*)(WH + (ct1 * 16 + lm) * 128 + ksl * 32 + 8 * g);
            bf16x8 Al1 = *(const bf16x8*)(WL + (ct1 * 16 + lm) * 128 + ksl * 32 + 8 * g);
            a0 = __builtin_amdgcn_mfma_f32_16x16x32_bf16(Ah0, bhi[ksl], a0, 0, 0, 0);
            a1 = __builtin_amdgcn_mfma_f32_16x16x32_bf16(Ah1, bhi[ksl], a1, 0, 0, 0);
            a0 = __builtin_amdgcn_mfma_f32_16x16x32_bf16(Ah0, blo[ksl], a0, 0, 0, 0);
            a1 = __builtin_amdgcn_mfma_f32_16x16x32_bf16(Ah1, blo[ksl], a1, 0, 0, 0);
            a0 = __builtin_amdgcn_mfma_f32_16x16x32_bf16(Al0, bhi[ksl], a0, 0, 0, 0);
            a1 = __builtin_amdgcn_mfma_f32_16x16x32_bf16(Al1, bhi[ksl], a1, 0, 0, 0);
        }
        float q0[4], q1[4];
#pragma unroll
        for (int r = 0; r < 4; r++) {
            int c0 = ct0 * 16 + 4 * g + r, c1 = ct1 * 16 + 4 * g + r;
            q0[r] = a0[r] + bq[p * 128 + c0];
            q1[r] = a1[r] + bq[p * 128 + c1];
            qbuf[((long long)pb * 128 + c0) * HW + m] = q0[r];
            qbuf[((long long)pb * 128 + c1) * HW + m] = q1[r];
        }
        unsigned short* Yb = qbf + ((long long)pb * HW + m) * 128;
        *(unsigned*)(Yb + ct0 * 16 + 4 * g) =
            (unsigned)f2bf(q0[0] * SCALE) | ((unsigned)f2bf(q0[1] * SCALE) << 16);
        *(unsigned*)(Yb + ct0 * 16 + 4 * g + 2) =
            (unsigned)f2bf(q0[2] * SCALE) | ((unsigned)f2bf(q0[3] * SCALE) << 16);
        *(unsigned*)(Yb + ct1 * 16 + 4 * g) =
            (unsigned)f2bf(q1[0] * SCALE) | ((unsigned)f2bf(q1[1] * SCALE) << 16);
        *(unsigned*)(Yb + ct1 * 16 + 4 * g + 2) =
            (unsigned)f2bf(q1[2] * SCALE) | ((unsigned)f2bf(q1[3] * SCALE) << 16);
    }
}

// ---------------------------------------------------------------------------
// 3a) depthwise 4x4 s4 conv, coalesced via LDS row staging.
//     block = (pb, hk); 4 c-quarters sequentially. off[pb][s][c] = dw + bias.
__global__ __launch_bounds__(256) void offset_dw(const float* __restrict__ qbuf,
                                                 const float* __restrict__ dw_w,
                                                 const float* __restrict__ dw_b,
                                                 float* __restrict__ off) {
    __shared__ float ld[32][4][65];
    int blk = blockIdx.x;                 // 12*16
    int pb = blk >> 4;
    int hk = blk & 15;
    int p = pb >> 2;
    int tid = threadIdx.x;
    for (int cq = 0; cq < 4; cq++) {
        int c32 = cq * 32;
        __syncthreads();
#pragma unroll
        for (int it = 0; it < 8; it++) {
            int i2 = tid + it * 256;          // 2048 float4
            int c = i2 >> 6, rem = i2 & 63;
            int y = rem >> 4, xq = rem & 15;
            float4 v = *(const float4*)(qbuf + ((long long)pb * 128 + c32 + c) * HW
                                        + (4 * hk + y) * 64 + xq * 4);
            ld[c][y][xq * 4 + 0] = v.x;
            ld[c][y][xq * 4 + 1] = v.y;
            ld[c][y][xq * 4 + 2] = v.z;
            ld[c][y][xq * 4 + 3] = v.w;
        }
        __syncthreads();
        int wk = tid >> 4;
#pragma unroll
        for (int oi = 0; oi < 2; oi++) {
            int c = (tid & 15) + oi * 16;
            const float* dwp = dw_w + (p * 128 + c32 + c) * 16;
            float acc = dw_b[p * 128 + c32 + c];
#pragma unroll
            for (int ky = 0; ky < 4; ky++)
#pragma unroll
                for (int kx = 0; kx < 4; kx++)
                    acc += ld[c][ky][wk * 4 + kx] * dwp[ky * 4 + kx];
            off[((long long)pb * 256 + hk * 16 + wk) * 128 + c32 + c] = acc;
        }
    }
}

// ---------------------------------------------------------------------------
// 3b) LN -> GELU -> 1x1 to 2 -> pos + attn bias params. One wave per (pb,s).
__global__ __launch_bounds__(64) void offset_ln(const float* __restrict__ off,
                                                const float* __restrict__ ln_g,
                                                const float* __restrict__ ln_b,
                                                const float* __restrict__ pw_w,
                                                float* __restrict__ posb,
                                                uint4* __restrict__ prmb) {
    int blk = blockIdx.x;                 // 3072
    int pb = blk >> 8;
    int s = blk & 255;
    int p = pb >> 2;
    int hk = s >> 4, wk = s & 15;
    int lane = threadIdx.x;
    const float* op = off + ((long long)pb * 256 + s) * 128;
    float a0 = op[lane], a1 = op[lane + 64];
    float s1 = a0 + a1;
#pragma unroll
    for (int o = 1; o < 64; o <<= 1) s1 += __shfl_xor(s1, o);
    float mu = s1 * (1.f / 128.f);
    float d0 = a0 - mu, d1 = a1 - mu;
    float v2 = d0 * d0 + d1 * d1;
#pragma unroll
    for (int o = 1; o < 64; o <<= 1) v2 += __shfl_xor(v2, o);
    float rs = rsqrtf(v2 * (1.f / 128.f) + 1e-5f);
    int c0 = lane, c1 = lane + 64;
    float y0 = d0 * rs * ln_g[p * 128 + c0] + ln_b[p * 128 + c0];
    float y1 = d1 * rs * ln_g[p * 128 + c1] + ln_b[p * 128 + c1];
    float g0 = 0.5f * y0 * (1.f + erff(y0 * 0.70710678118654752f));
    float g1 = 0.5f * y1 * (1.f + erff(y1 * 0.70710678118654752f));
    float o0 = pw_w[(p * 2 + 0) * 128 + c0] * g0 + pw_w[(p * 2 + 0) * 128 + c1] * g1;
    float o1 = pw_w[(p * 2 + 1) * 128 + c0] * g0 + pw_w[(p * 2 + 1) * 128 + c1] * g1;
#pragma unroll
    for (int o = 1; o < 64; o <<= 1) o0 += __shfl_xor(o0, o);
#pragma unroll
    for (int o = 1; o < 64; o <<= 1) o1 += __shfl_xor(o1, o);
    if (lane == 0) {
        float refy = (hk + 0.5f) * (2.f / 15.f) - 1.f;
        float refx = (wk + 0.5f) * (2.f / 15.f) - 1.f;
        float py = fminf(fmaxf(o0 + refy, -1.f), 1.f);
        float px = fminf(fmaxf(o1 + refx, -1.f), 1.f);
        int pbn = pb * 256 + s;
        posb[pbn * 2 + 0] = py;
        posb[pbn * 2 + 1] = px;
        float cy = 31.5f * (1.f - py), cx = 31.5f * (1.f - px);
        float yf = floorf(cy), xf = floorf(cx);
        float wy = cy - yf, wx = cx - xf;
        int Y0 = (int)yf, X0 = (int)xf;
        uint4 v;
        v.x = (unsigned)f2bf((1.f - wy) * (1.f - wx))
            | ((unsigned)f2bf((1.f - wy) * wx) << 16);
        v.y = (unsigned)f2bf(wy * (1.f - wx))
            | ((unsigned)f2bf(wy * wx) << 16);
        v.z = (unsigned)((Y0 * 128 + X0) * 2);
        v.w = 0;
        prmb[pbn] = v;
    }
}

// ---------------------------------------------------------------------------
// 3c) transpose x0,x1 chans 0:128 -> xT bf16 [v][b][m][c] (for coalesced
//     corner-row sampling).
__global__ __launch_bounds__(256) void trans_x(const float* __restrict__ x0,
                                               const float* __restrict__ x1,
                                               unsigned short* __restrict__ xT) {
    __shared__ float ld[32][65];
    int blk = blockIdx.x;                 // 2048
    int v = blk >> 10;
    int rem = blk & 1023;
    int b = rem >> 8;
    int rem2 = rem & 255;
    int ct = rem2 >> 6;                   // c-tile of 32
    int mt = rem2 & 63;                   // m-tile of 64
    const float* src = ((v == 0) ? x0 : x1) + (long long)b * CC * HW
                       + (long long)(ct * 32) * HW + mt * 64;
    int tid = threadIdx.x;
#pragma unroll
    for (int it = 0; it < 2; it++) {
        int c = tid >> 3, x4 = (tid & 7) + it * 8;
        float4 w = *(const float4*)(src + (long long)c * HW + x4 * 4);
        ld[c][x4 * 4 + 0] = w.x;
        ld[c][x4 * 4 + 1] = w.y;
        ld[c][x4 * 4 + 2] = w.z;
        ld[c][x4 * 4 + 3] = w.w;
    }
    __syncthreads();
    int m = tid >> 2, cg = tid & 3;
    union { unsigned u[4]; } pk;
#pragma unroll
    for (int t = 0; t < 4; t++) {
        unsigned short h0 = f2bf(ld[cg * 8 + 2 * t][m]);
        unsigned short h1 = f2bf(ld[cg * 8 + 2 * t + 1][m]);
        pk.u[t] = (unsigned)h0 | ((unsigned)h1 << 16);
    }
    *(uint4*)(xT + (((long long)(v * 4 + b)) * HW + mt * 64 + m) * 128
              + ct * 32 + cg * 8) = *(uint4*)pk.u;
}

// ---------------------------------------------------------------------------
// 4+5) fused sample + K/V conv (MFMA). Block = (pb, n-tile of 32).
//     Phase A: bilinear-sample 32 n x 128 c from xT into LDS (bf16, swizzled).
//     CLAMPED base corner (<=62) with fraction vs clamped base: exact at the
//     grid edge (weight 1 on row/col 63), and all 4 corner reads in-bounds.
//     Phase B: K = mfma(xs, Wk) -> kbf [n][c]; V = mfma(Wv, xs) -> vbf [c][n].
__global__ __launch_bounds__(256) void sample_kv(const unsigned short* __restrict__ xT,
                                                 const float* __restrict__ posb,
                                                 const unsigned short* __restrict__ wkh,
                                                 const unsigned short* __restrict__ wvh,
                                                 const float* __restrict__ bk,
                                                 const float* __restrict__ bv,
                                                 unsigned short* __restrict__ kbf,
                                                 unsigned short* __restrict__ vbf) {
    __shared__ unsigned short xls[32 * 128];      // 8 KB, XOR-swizzled rows
    int blk = blockIdx.x;                 // 96
    int pb = blk >> 3;
    int nt = blk & 7;
    int p = pb >> 2, b = pb & 3;
    int n0 = nt * 32;
    int tid = threadIdx.x;

    // ---- Phase A ----
    {
        int nl = tid >> 3, co = tid & 7;
        int n = n0 + nl;
        float py = posb[(pb * 256 + n) * 2 + 0];
        float px = posb[(pb * 256 + n) * 2 + 1];
        float yi = (py + 1.f) * 31.5f, xi = (px + 1.f) * 31.5f;
        yi = fminf(fmaxf(yi, 0.f), 63.f);
        xi = fminf(fmaxf(xi, 0.f), 63.f);
        int y0 = min((int)yi, 62);            // clamped base corner
        int x0i = min((int)xi, 62);
        float wy = yi - (float)y0, wx = xi - (float)x0i;
        float w00 = (1.f - wy) * (1.f - wx), w01 = (1.f - wy) * wx;
        float w10 = wy * (1.f - wx), w11 = wy * wx;
        int vsel = (p == 2) ? 1 : 0;
        const unsigned short* base = xT + ((long long)(vsel * 4 + b)) * HW * 128;
        int m00 = y0 * 64 + x0i;
        char* dst = (char*)xls;
#pragma unroll
        for (int cb = 0; cb < 2; cb++) {
            int c0 = co * 16 + cb * 8;
            bf16x8 a = *(const bf16x8*)(base + (long long)m00 * 128 + c0);
            bf16x8 bb = *(const bf16x8*)(base + (long long)(m00 + 1) * 128 + c0);
            bf16x8 cc = *(const bf16x8*)(base + (long long)(m00 + 64) * 128 + c0);
            bf16x8 dd = *(const bf16x8*)(base + (long long)(m00 + 65) * 128 + c0);
            union { unsigned u[4]; bf16x8 v; } R;
#pragma unroll
            for (int t = 0; t < 4; t++) {
                float r0 = w00 * bflo((unsigned)(unsigned short)a[2 * t])
                         + w01 * bflo((unsigned)(unsigned short)bb[2 * t])
                         + w10 * bflo((unsigned)(unsigned short)cc[2 * t])
                         + w11 * bflo((unsigned)(unsigned short)dd[2 * t]);
                float r1 = w00 * bflo((unsigned)(unsigned short)a[2 * t + 1])
                         + w01 * bflo((unsigned)(unsigned short)bb[2 * t + 1])
                         + w10 * bflo((unsigned)(unsigned short)cc[2 * t + 1])
                         + w11 * bflo((unsigned)(unsigned short)dd[2 * t + 1]);
                R.u[t] = (unsigned)f2bf(r0) | ((unsigned)f2bf(r1) << 16);
            }
            *(bf16x8*)(dst + ((nl * 256 + c0 * 2) ^ ((nl & 7) << 4))) = R.v;
        }
    }
    __syncthreads();

    // ---- Phase B ----
    int wid = tid >> 6, lane = tid & 63;
    int g = lane >> 4, lm = lane & 15;
    int ntile = wid & 1, isv = wid >> 1;
    int nl = ntile * 16 + lm;
    const char* srcl = (const char*)xls;
    bf16x8 xf[4];
#pragma unroll
    for (int ks = 0; ks < 4; ks++)
        xf[ks] = *(const bf16x8*)(srcl + ((nl * 256 + (ks * 32 + 8 * g) * 2)
                                          ^ ((nl & 7) << 4)));
    f32x4 zero = {0.f, 0.f, 0.f, 0.f};
    if (!isv) {
        const unsigned short* WK = wkh + p * 16384;
#pragma unroll
        for (int ct = 0; ct < 8; ct++) {
            f32x4 acc = zero;
#pragma unroll
            for (int ks = 0; ks < 4; ks++) {
                bf16x8 wf = *(const bf16x8*)(WK + (ct * 16 + lm) * 128 + ks * 32 + 8 * g);
                acc = __builtin_amdgcn_mfma_f32_16x16x32_bf16(xf[ks], wf, acc, 0, 0, 0);
            }
            float bias = bk[p * 128 + ct * 16 + lm];
#pragma unroll
            for (int r = 0; r < 4; r++) {
                int n = n0 + ntile * 16 + 4 * g + r;
                kbf[((long long)pb * 256 + n) * 128 + ct * 16 + lm] = f2bf(acc[r] + bias);
            }
        }
    } else {
        const unsigned short* WV = wvh + p * 16384;
#pragma unroll
        for (int ct = 0; ct < 8; ct++) {
            f32x4 acc = zero;
#pragma unroll
            for (int ks = 0; ks < 4; ks++) {
                bf16x8 wf = *(const bf16x8*)(WV + (ct * 16 + lm) * 128 + ks * 32 + 8 * g);
                acc = __builtin_amdgcn_mfma_f32_16x16x32_bf16(wf, xf[ks], acc, 0, 0, 0);
            }
#pragma unroll
            for (int r = 0; r < 4; r++) {
                int c = ct * 16 + 4 * g + r;
                vbf[((long long)pb * 128 + c) * 256 + n0 + ntile * 16 + lm]
                    = f2bf(acc[r] + bv[p * 128 + c]);
            }
        }
    }
}

// ---------------------------------------------------------------------------
// 6) MFMA attention (R5 config: 256 thr, 4 waves, 36KB LDS, 4 blocks/CU).
__global__ __launch_bounds__(256, 4) void attn_mfma(
        const unsigned short* __restrict__ qbf,
        const unsigned short* __restrict__ kbf,
        const unsigned short* __restrict__ vbf,
        const unsigned short* __restrict__ tabbf,
        const uint4* __restrict__ prmb,
        float* __restrict__ obuf) {
    __shared__ unsigned short tab[16384];     // 32 KB
    __shared__ uint4 prm[256];                // 4 KB
    int tid = threadIdx.x;
    int wid = tid >> 6, lane = tid & 63;
    int g = lane >> 4, lm = lane & 15;
    int bid = blockIdx.x;                     // 3072
    int my = bid & 63;
    int h = (bid >> 6) & 3;
    int b = (bid >> 8) & 3;
    int p = bid >> 10;
    int pb = p * 4 + b;

    {   // stage table + params
        const uint4* ts = (const uint4*)(tabbf + (long long)(p * 4 + h) * 16384);
        uint4* td = (uint4*)tab;
#pragma unroll
        for (int i = 0; i < 8; i++) td[tid + i * 256] = ts[tid + i * 256];
        prm[tid] = prmb[pb * 256 + tid];
    }
    __syncthreads();

    int mx = (wid << 4) + lm;

    // ---- QK^T (swapped): A = K[n][c], B = Q^T[c][m]; q pre-scaled ----
    bf16x8 qf = *(const bf16x8*)(qbf + ((long long)pb * HW + my * 64 + mx) * 128
                                 + h * 32 + 8 * g);
    const unsigned short* kbase = kbf + ((long long)pb * 256 + lm) * 128
                                  + h * 32 + 8 * g;
    f32x4 zero = {0.f, 0.f, 0.f, 0.f};
    f32x4 acc[16];
#pragma unroll
    for (int ni = 0; ni < 16; ni++) {
        bf16x8 kf = *(const bf16x8*)(kbase + ni * 16 * 128);
        acc[ni] = __builtin_amdgcn_mfma_f32_16x16x32_bf16(kf, qf, zero, 0, 0, 0);
    }

    // ---- RPE bias from LDS table ----
    int laneoff = (my * 128 + mx) * 2;
    const char* tb = (const char*)tab;
#pragma unroll
    for (int ni = 0; ni < 16; ni++) {
#pragma unroll
        for (int r = 0; r < 4; r++) {
            int n = ni * 16 + 4 * g + r;
            uint4 pw = prm[n];
            int va = (int)pw.z + laneoff;
            float a0 = bflo(*(const unsigned short*)(tb + va));
            float a1 = bflo(*(const unsigned short*)(tb + va + 2));
            float b0 = bflo(*(const unsigned short*)(tb + va + 256));
            float b1 = bflo(*(const unsigned short*)(tb + va + 258));
            float t = fmaf(bflo(pw.x), a0, acc[ni][r]);
            t = fmaf(bfhi(pw.x), a1, t);
            t = fmaf(bflo(pw.y), b0, t);
            t = fmaf(bfhi(pw.y), b1, t);
            acc[ni][r] = t;
        }
    }

    // ---- softmax over n ----
    float mxv = -1e30f;
#pragma unroll
    for (int ni = 0; ni < 16; ni++)
        mxv = fmaxf(mxv, fmaxf(fmaxf(acc[ni][0], acc[ni][1]),
                               fmaxf(acc[ni][2], acc[ni][3])));
    mxv = fmaxf(mxv, __shfl_xor(mxv, 16));
    mxv = fmaxf(mxv, __shfl_xor(mxv, 32));
    float sum = 0.f;
    unsigned dwA[16], dwB[16];
#pragma unroll
    for (int ni = 0; ni < 16; ni++) {
        float e0 = __expf(acc[ni][0] - mxv);
        float e1 = __expf(acc[ni][1] - mxv);
        float e2 = __expf(acc[ni][2] - mxv);
        float e3 = __expf(acc[ni][3] - mxv);
        sum += (e0 + e1) + (e2 + e3);
        asm("v_cvt_pk_bf16_f32 %0, %1, %2" : "=v"(dwA[ni]) : "v"(e0), "v"(e1));
        asm("v_cvt_pk_bf16_f32 %0, %1, %2" : "=v"(dwB[ni]) : "v"(e2), "v"(e3));
    }
    sum += __shfl_xor(sum, 16);
    sum += __shfl_xor(sum, 32);

    // ---- PV: pf assembled via shfl exchange ----
    int src0 = ((g & 1) << 5) + lm;
    int src1 = src0 + 16;
    bool sel = (g >> 1) != 0;
    const unsigned short* vb0 = vbf + ((long long)pb * 128 + h * 32 + lm) * 256
                                + 8 * g;
    f32x4 o0 = zero, o1 = zero;
#pragma unroll
    for (int st = 0; st < 8; st++) {
        unsigned d0a = __shfl(dwA[2 * st], src0), d0b = __shfl(dwA[2 * st + 1], src0);
        unsigned d1a = __shfl(dwB[2 * st], src0), d1b = __shfl(dwB[2 * st + 1], src0);
        unsigned d2a = __shfl(dwA[2 * st], src1), d2b = __shfl(dwA[2 * st + 1], src1);
        unsigned d3a = __shfl(dwB[2 * st], src1), d3b = __shfl(dwB[2 * st + 1], src1);
        union { unsigned u[4]; bf16x8 v; } pf;
        pf.u[0] = sel ? d0b : d0a;
        pf.u[1] = sel ? d1b : d1a;
        pf.u[2] = sel ? d2b : d2a;
        pf.u[3] = sel ? d3b : d3a;
        bf16x8 v0 = *(const bf16x8*)(vb0 + st * 32);
        bf16x8 v1 = *(const bf16x8*)(vb0 + 4096 + st * 32);
        o0 = __builtin_amdgcn_mfma_f32_16x16x32_bf16(v0, pf.v, o0, 0, 0, 0);
        o1 = __builtin_amdgcn_mfma_f32_16x16x32_bf16(v1, pf.v, o1, 0, 0, 0);
    }

    float inv = 1.f / sum;
    float* ob = obuf + ((long long)pb * 128 + h * 32) * HW + my * 64 + mx;
#pragma unroll
    for (int r = 0; r < 4; r++) {
        ob[(g * 4 + r) * HW] = o0[r] * inv;
        ob[(16 + g * 4 + r) * HW] = o1[r] * inv;
    }
}

// ---------------------------------------------------------------------------
// 7) conv_wo via MFMA (bf16): out = x + sum_p Wo[p] o[p] + bo on chans
//    128:256 of vars 1,2.
__global__ __launch_bounds__(256) void conv_wo(const float* __restrict__ x1,
                                               const float* __restrict__ x2,
                                               const float* __restrict__ obuf,
                                               const unsigned short* __restrict__ woh,
                                               const float* __restrict__ bo,
                                               float* __restrict__ out) {
    int wid = threadIdx.x >> 6, lane = threadIdx.x & 63;
    int g = lane >> 4, lm = lane & 15;
    int gw = blockIdx.x * 4 + wid;            // 2048 waves
    int mt = gw & 255;
    int b = (gw >> 8) & 3;
    int vs = gw >> 10;                        // 0 -> var1, 1 -> var2
    int m = mt * 16 + lm;
    int np = vs + 1;

    f32x4 acc[8];
#pragma unroll
    for (int ct = 0; ct < 8; ct++) acc[ct] = (f32x4){0.f, 0.f, 0.f, 0.f};

    for (int pi = 0; pi < np; pi++) {
        int p = vs ? (1 + pi) : 0;
        const float* O = obuf + (long long)(p * 4 + b) * 128 * HW;
        bf16x8 bh[4];
#pragma unroll
        for (int ksl = 0; ksl < 4; ksl++) {
            float v[8];
#pragma unroll
            for (int j = 0; j < 8; j++)
                v[j] = O[(long long)(ksl * 32 + 8 * g + j) * HW + m];
            union { unsigned u[4]; bf16x8 v; } H;
#pragma unroll
            for (int t = 0; t < 4; t++)
                H.u[t] = (unsigned)f2bf(v[2 * t]) | ((unsigned)f2bf(v[2 * t + 1]) << 16);
            bh[ksl] = H.v;
        }
        const unsigned short* WH = woh + p * 16384;
#pragma unroll
        for (int ct = 0; ct < 8; ct++)
#pragma unroll
            for (int ksl = 0; ksl < 4; ksl++) {
                bf16x8 A = *(const bf16x8*)(WH + (ct * 16 + lm) * 128 + ksl * 32 + 8 * g);
                acc[ct] = __builtin_amdgcn_mfma_f32_16x16x32_bf16(A, bh[ksl], acc[ct], 0, 0, 0);
            }
    }

    int qi = vs + 1;
    const float* xq = (vs ? x2 : x1) + (long long)b * CC * HW;
#pragma unroll
    for (int ct = 0; ct < 8; ct++)
#pragma unroll
        for (int r = 0; r < 4; r++) {
            int c = ct * 16 + 4 * g + r;
            float bias = vs ? (bo[128 + c] + bo[256 + c]) : bo[c];
            float base = xq[(long long)(128 + c) * HW + m];
            out[(((long long)(qi * 4 + b)) * CC + 128 + c) * HW + m]
                = base + acc[ct][r] + bias;
        }
}

// ---------------------------------------------------------------------------
extern "C" void kernel_launch(void* const* d_in, const int* in_sizes, int n_in,
                              void* d_out, int out_size, void* d_ws, size_t ws_size,
                              hipStream_t stream) {
    const float* x0 = (const float*)d_in[0];
    const float* x1 = (const float*)d_in[1];
    const float* x2 = (const float*)d_in[2];
    const float* Wq = (const float*)d_in[3];
    const float* bq = (const float*)d_in[4];
    const float* Wk = (const float*)d_in[5];
    const float* bk = (const float*)d_in[6];
    const float* Wv = (const float*)d_in[7];
    const float* bv = (const float*)d_in[8];
    const float* Wo = (const float*)d_in[9];
    const float* bo = (const float*)d_in[10];
    const float* dw_w = (const float*)d_in[11];
    const float* dw_b = (const float*)d_in[12];
    const float* ln_g = (const float*)d_in[13];
    const float* ln_b = (const float*)d_in[14];
    const float* pw_w = (const float*)d_in[15];
    const float* rpe = (const float*)d_in[16];
    float* out = (float*)d_out;

    // Region A (24 MB): qbuf f32 -> xT bf16 -> obuf f32, stream-ordered
    // disjoint lifetimes (qbuf dead after offset_dw; xT dead after sample_kv).
    float* ws = (float*)d_ws;
    float* qbuf = ws;                                   // 6291456 f
    unsigned short* xT = (unsigned short*)ws;           // 4194304 s (alias)
    float* obuf = ws;                                   // alias
    float* posb = ws + 6291456;                         // 6144 f
    float* off  = posb + 6144;                          // 393216 f
    unsigned short* qbf = (unsigned short*)(off + 393216);   // 12582912 s
    unsigned short* kbf = qbf + 12582912;                    // 393216 s
    unsigned short* vbf = kbf + 393216;                      // 393216 s
    unsigned short* tabbf = vbf + 393216;                    // 196608 s
    uint4* prmb = (uint4*)(tabbf + 196608);                  // 3072 uint4
    unsigned short* wqh = (unsigned short*)(prmb + 3072);    // 49152 s
    unsigned short* wql = wqh + 49152;
    unsigned short* woh = wql + 49152;
    unsigned short* wkh = woh + 49152;
    unsigned short* wvh = wkh + 49152;

    copy_init<<<1024, 256, 0, stream>>>(x0, out);
    prep_const<<<24, 256, 0, stream>>>(rpe, Wq, Wo, Wk, Wv, tabbf,
                                       wqh, wql, woh, wkh, wvh);
    conv_q<<<768, 256, 0, stream>>>(x1, x2, wqh, wql, bq, qbuf, qbf, out);
    offset_dw<<<192, 256, 0, stream>>>(qbuf, dw_w, dw_b, off);
    offset_ln<<<3072, 64, 0, stream>>>(off, ln_g, ln_b, pw_w, posb, prmb);
    trans_x<<<2048, 256, 0, stream>>>(x0, x1, xT);
    sample_kv<<<96, 256, 0, stream>>>(xT, posb, wkh, wvh, bk, bv, kbf, vbf);
    attn_mfma<<<3072, 256, 0, stream>>>(qbf, kbf, vbf, tabbf, prmb, obuf);
    conv_wo<<<512, 256, 0, stream>>>(x1, x2, obuf, woh, bo, out);
}

// Round 9
// 181.597 us; speedup vs baseline: 2.0036x; 1.0388x over previous
//
#include <hip/hip_runtime.h>
#include <math.h>

// Problem constants
#define NVAR 3
#define BB 4
#define CC 256
#define C1 128
#define HEADS 4
#define HH 64
#define WW 64
#define HW 4096
#define RPE_W 127
#define NP 3
#define SCALE 0.17677669529663687f
// pairs: p=0 -> (i=1,j=0), p=1 -> (i=2,j=0), p=2 -> (i=2,j=1)

typedef short bf16x8 __attribute__((ext_vector_type(8)));
typedef float f32x4 __attribute__((ext_vector_type(4)));
typedef __bf16 bf16x2 __attribute__((ext_vector_type(2)));

__device__ __forceinline__ unsigned short f2bf(float f) {
    unsigned int u = __float_as_uint(f);
    u += 0x7fffu + ((u >> 16) & 1u);          // round-to-nearest-even
    return (unsigned short)(u >> 16);
}
__device__ __forceinline__ float bflo(unsigned u) { return __uint_as_float(u << 16); }
__device__ __forceinline__ float bfhi(unsigned u) { return __uint_as_float(u & 0xffff0000u); }

// packed bf16x2 dot: c + a.lo*b.lo + a.hi*b.hi
__device__ __forceinline__ float dot2bf(unsigned a, unsigned b, float c) {
#if __has_builtin(__builtin_amdgcn_fdot2_f32_bf16)
    return __builtin_amdgcn_fdot2_f32_bf16(__builtin_bit_cast(bf16x2, a),
                                           __builtin_bit_cast(bf16x2, b), c, false);
#else
    return c + bflo(a) * bflo(b) + bfhi(a) * bfhi(b);
#endif
}

// ---------------------------------------------------------------------------
// K1) const prep (blocks 0..23) + copy x0 -> out var0 + flow zeros (24..1047)
__global__ __launch_bounds__(256) void prep_copy(const float* __restrict__ rpe,
                                                 const float* __restrict__ Wq,
                                                 const float* __restrict__ Wo,
                                                 const float* __restrict__ Wk,
                                                 const float* __restrict__ Wv,
                                                 const float* __restrict__ x0,
                                                 unsigned short* __restrict__ tabbf,
                                                 unsigned short* __restrict__ wqh,
                                                 unsigned short* __restrict__ wql,
                                                 unsigned short* __restrict__ woh,
                                                 unsigned short* __restrict__ wkh,
                                                 unsigned short* __restrict__ wvh,
                                                 float* __restrict__ out) {
    int blk = blockIdx.x;
    if (blk >= 24) {
        const long long n4 = (long long)BB * CC * HW / 4;
        long long i = (long long)(blk - 24) * 256 + threadIdx.x;
        const long long stride = 1024LL * 256;
        for (; i < n4 + 12; i += stride) {
            if (i < n4) ((float4*)out)[i] = ((const float4*)x0)[i];
            else out[3LL * BB * CC * HW + (i - n4)] = 0.f;
        }
        return;
    }
    if (blk < 12) {
        const float* src = rpe + (long long)blk * RPE_W * RPE_W;
        unsigned short* dst = tabbf + (long long)blk * 16384;
        for (int idx = threadIdx.x; idx < 16384; idx += 256) {
            int y = idx >> 7, x = idx & 127;
            float v = (y < RPE_W && x < RPE_W) ? src[y * RPE_W + x] : 0.f;
            dst[idx] = f2bf(v);
        }
    } else if (blk < 15) {
        int p = blk - 12;
        for (int i = threadIdx.x; i < 16384; i += 256) {
            float w = Wq[p * 16384 + i];
            unsigned short h = f2bf(w);
            wqh[p * 16384 + i] = h;
            wql[p * 16384 + i] = f2bf(w - bflo((unsigned)h));
        }
    } else if (blk < 18) {
        int p = blk - 15;
        for (int i = threadIdx.x; i < 16384; i += 256)
            woh[p * 16384 + i] = f2bf(Wo[p * 16384 + i]);
    } else if (blk < 21) {
        int p = blk - 18;
        for (int i = threadIdx.x; i < 16384; i += 256)
            wkh[p * 16384 + i] = f2bf(Wk[p * 16384 + i]);
    } else {
        int p = blk - 21;
        for (int i = threadIdx.x; i < 16384; i += 256)
            wvh[p * 16384 + i] = f2bf(Wv[p * 16384 + i]);
    }
}

// ---------------------------------------------------------------------------
// K2) conv_q via MFMA, split bf16 (hi+lo). Outputs qbuf f32 [pb][c][m],
//     qbf bf16 [pb][m][c] (pre-scaled), AND copies x chans 0:128 into out.
__global__ __launch_bounds__(256) void conv_q(const float* __restrict__ x1,
                                              const float* __restrict__ x2,
                                              const unsigned short* __restrict__ wqh,
                                              const unsigned short* __restrict__ wql,
                                              const float* __restrict__ bq,
                                              float* __restrict__ qbuf,
                                              unsigned short* __restrict__ qbf,
                                              float* __restrict__ out) {
    int wid = threadIdx.x >> 6, lane = threadIdx.x & 63;
    int g = lane >> 4, lm = lane & 15;
    int gw = blockIdx.x * 4 + wid;            // 3072 waves
    int mt = gw & 255;
    int pb = gw >> 8;
    int p = pb >> 2, b = pb & 3;
    const float* X = ((p == 0) ? x1 : x2) + (long long)b * CC * HW;
    int m = mt * 16 + lm;
    float* outc = (p < 2)
        ? out + (((long long)((p + 1) * 4 + b)) * CC) * HW + m
        : nullptr;

    bf16x8 bhi[4], blo[4];
#pragma unroll
    for (int ksl = 0; ksl < 4; ksl++) {
        float v[8];
#pragma unroll
        for (int j = 0; j < 8; j++) {
            int k = ksl * 32 + 8 * g + j;
            v[j] = X[(long long)k * HW + m];
            if (outc) outc[(long long)k * HW] = v[j];
        }
        union { unsigned u[4]; bf16x8 v; } H, L;
#pragma unroll
        for (int t = 0; t < 4; t++) {
            unsigned short h0 = f2bf(v[2 * t]), h1 = f2bf(v[2 * t + 1]);
            unsigned short l0 = f2bf(v[2 * t] - bflo((unsigned)h0));
            unsigned short l1 = f2bf(v[2 * t + 1] - bflo((unsigned)h1));
            H.u[t] = (unsigned)h0 | ((unsigned)h1 << 16);
            L.u[t] = (unsigned)l0 | ((unsigned)l1 << 16);
        }
        bhi[ksl] = H.v;
        blo[ksl] = L.v;
    }

    const unsigned short* WH = wqh + p * 16384;
    const unsigned short* WL = wql + p * 16384;
    f32x4 zero = {0.f, 0.f, 0.f, 0.f};
#pragma unroll
    for (int ct2 = 0; ct2 < 4; ct2++) {
        int ct0 = 2 * ct2, ct1 = ct0 + 1;
        f32x4 a0 = zero, a1 = zero;
#pragma unroll
        for (int ksl = 0; ksl < 4; ksl++) {
            bf16x8 Ah0 = *(const bf16x8*)(WH + (ct0 * 16 + lm) * 128 + ksl * 32 + 8 * g);
            bf16x8 Al0 = *(const bf16x8*)(WL + (ct0 * 16 + lm) * 128 + ksl * 32 + 8 * g);
            bf16x8 Ah1 = *(const bf16x8*)(WH + (ct1 * 16 + lm) * 128 + ksl * 32 + 8 * g);
            bf16x8 Al1 = *(const bf16x8*)(WL + (ct1 * 16 + lm) * 128 + ksl * 32 + 8 * g);
            a0 = __builtin_amdgcn_mfma_f32_16x16x32_bf16(Ah0, bhi[ksl], a0, 0, 0, 0);
            a1 = __builtin_amdgcn_mfma_f32_16x16x32_bf16(Ah1, bhi[ksl], a1, 0, 0, 0);
            a0 = __builtin_amdgcn_mfma_f32_16x16x32_bf16(Ah0, blo[ksl], a0, 0, 0, 0);
            a1 = __builtin_amdgcn_mfma_f32_16x16x32_bf16(Ah1, blo[ksl], a1, 0, 0, 0);
            a0 = __builtin_amdgcn_mfma_f32_16x16x32_bf16(Al0, bhi[ksl], a0, 0, 0, 0);
            a1 = __builtin_amdgcn_mfma_f32_16x16x32_bf16(Al1, bhi[ksl], a1, 0, 0, 0);
        }
        float q0[4], q1[4];
#pragma unroll
        for (int r = 0; r < 4; r++) {
            int c0 = ct0 * 16 + 4 * g + r, c1 = ct1 * 16 + 4 * g + r;
            q0[r] = a0[r] + bq[p * 128 + c0];
            q1[r] = a1[r] + bq[p * 128 + c1];
            qbuf[((long long)pb * 128 + c0) * HW + m] = q0[r];
            qbuf[((long long)pb * 128 + c1) * HW + m] = q1[r];
        }
        unsigned short* Yb = qbf + ((long long)pb * HW + m) * 128;
        *(unsigned*)(Yb + ct0 * 16 + 4 * g) =
            (unsigned)f2bf(q0[0] * SCALE) | ((unsigned)f2bf(q0[1] * SCALE) << 16);
        *(unsigned*)(Yb + ct0 * 16 + 4 * g + 2) =
            (unsigned)f2bf(q0[2] * SCALE) | ((unsigned)f2bf(q0[3] * SCALE) << 16);
        *(unsigned*)(Yb + ct1 * 16 + 4 * g) =
            (unsigned)f2bf(q1[0] * SCALE) | ((unsigned)f2bf(q1[1] * SCALE) << 16);
        *(unsigned*)(Yb + ct1 * 16 + 4 * g + 2) =
            (unsigned)f2bf(q1[2] * SCALE) | ((unsigned)f2bf(q1[3] * SCALE) << 16);
    }
}

// ---------------------------------------------------------------------------
// K3) fused middle kernel:
//   blocks 0..191:  offset net (depthwise conv staged in LDS -> LN -> GELU ->
//                   1x1 -> pos + prm), per (pb,hk); 'off' never leaves LDS.
//   blocks 192..2239: transpose x0,x1 chans 0:128 -> xT bf16 [v][b][m][c].
__global__ __launch_bounds__(256) void mid_kernel(const float* __restrict__ qbuf,
                                                  const float* __restrict__ dw_w,
                                                  const float* __restrict__ dw_b,
                                                  const float* __restrict__ ln_g,
                                                  const float* __restrict__ ln_b,
                                                  const float* __restrict__ pw_w,
                                                  const float* __restrict__ x0,
                                                  const float* __restrict__ x1,
                                                  float* __restrict__ posb,
                                                  uint4* __restrict__ prmb,
                                                  unsigned short* __restrict__ xT) {
    __shared__ float sm[32 * 4 * 65 + 16 * 128];     // 41.5 KB
    int blk = blockIdx.x;
    int tid = threadIdx.x;
    if (blk < 192) {
        float (*ld)[4][65] = (float(*)[4][65])sm;
        float (*dwout)[128] = (float(*)[128])(sm + 32 * 4 * 65);
        int pb = blk >> 4, hk = blk & 15;
        int p = pb >> 2;
        for (int cq = 0; cq < 4; cq++) {
            int c32 = cq * 32;
            __syncthreads();
#pragma unroll
            for (int it = 0; it < 8; it++) {
                int i2 = tid + it * 256;          // 2048 float4
                int c = i2 >> 6, rem = i2 & 63;
                int y = rem >> 4, xq = rem & 15;
                float4 v = *(const float4*)(qbuf + ((long long)pb * 128 + c32 + c) * HW
                                            + (4 * hk + y) * 64 + xq * 4);
                ld[c][y][xq * 4 + 0] = v.x;
                ld[c][y][xq * 4 + 1] = v.y;
                ld[c][y][xq * 4 + 2] = v.z;
                ld[c][y][xq * 4 + 3] = v.w;
            }
            __syncthreads();
            int wk = tid >> 4;
#pragma unroll
            for (int oi = 0; oi < 2; oi++) {
                int c = (tid & 15) + oi * 16;
                const float* dwp = dw_w + (p * 128 + c32 + c) * 16;
                float acc = dw_b[p * 128 + c32 + c];
#pragma unroll
                for (int ky = 0; ky < 4; ky++)
#pragma unroll
                    for (int kx = 0; kx < 4; kx++)
                        acc += ld[c][ky][wk * 4 + kx] * dwp[ky * 4 + kx];
                dwout[wk][c32 + c] = acc;
            }
        }
        __syncthreads();
        // LN phase: 4 waves x 4 wk each
        int wid = tid >> 6, lane = tid & 63;
        for (int i = 0; i < 4; i++) {
            int wk = wid * 4 + i;
            int s = hk * 16 + wk;
            float a0 = dwout[wk][lane], a1 = dwout[wk][lane + 64];
            float s1 = a0 + a1;
#pragma unroll
            for (int o = 1; o < 64; o <<= 1) s1 += __shfl_xor(s1, o);
            float mu = s1 * (1.f / 128.f);
            float d0 = a0 - mu, d1 = a1 - mu;
            float v2 = d0 * d0 + d1 * d1;
#pragma unroll
            for (int o = 1; o < 64; o <<= 1) v2 += __shfl_xor(v2, o);
            float rs = rsqrtf(v2 * (1.f / 128.f) + 1e-5f);
            int c0 = lane, c1 = lane + 64;
            float y0 = d0 * rs * ln_g[p * 128 + c0] + ln_b[p * 128 + c0];
            float y1 = d1 * rs * ln_g[p * 128 + c1] + ln_b[p * 128 + c1];
            float g0 = 0.5f * y0 * (1.f + erff(y0 * 0.70710678118654752f));
            float g1 = 0.5f * y1 * (1.f + erff(y1 * 0.70710678118654752f));
            float o0 = pw_w[(p * 2 + 0) * 128 + c0] * g0
                     + pw_w[(p * 2 + 0) * 128 + c1] * g1;
            float o1 = pw_w[(p * 2 + 1) * 128 + c0] * g0
                     + pw_w[(p * 2 + 1) * 128 + c1] * g1;
#pragma unroll
            for (int o = 1; o < 64; o <<= 1) o0 += __shfl_xor(o0, o);
#pragma unroll
            for (int o = 1; o < 64; o <<= 1) o1 += __shfl_xor(o1, o);
            if (lane == 0) {
                int wk2 = s & 15;
                float refy = (hk + 0.5f) * (2.f / 15.f) - 1.f;
                float refx = (wk2 + 0.5f) * (2.f / 15.f) - 1.f;
                float py = fminf(fmaxf(o0 + refy, -1.f), 1.f);
                float px = fminf(fmaxf(o1 + refx, -1.f), 1.f);
                int pbn = pb * 256 + s;
                posb[pbn * 2 + 0] = py;
                posb[pbn * 2 + 1] = px;
                float cy = 31.5f * (1.f - py), cx = 31.5f * (1.f - px);
                float yf = floorf(cy), xf = floorf(cx);
                float wy = cy - yf, wx = cx - xf;
                int Y0 = (int)yf, X0 = (int)xf;
                uint4 v;
                v.x = (unsigned)f2bf((1.f - wy) * (1.f - wx))
                    | ((unsigned)f2bf((1.f - wy) * wx) << 16);
                v.y = (unsigned)f2bf(wy * (1.f - wx))
                    | ((unsigned)f2bf(wy * wx) << 16);
                v.z = (unsigned)((Y0 * 128 + X0) * 2);
                v.w = 0;
                prmb[pbn] = v;
            }
        }
    } else {
        // transpose part
        float (*ld2)[65] = (float(*)[65])sm;
        int rem = blk - 192;                  // 0..2047
        int v = rem >> 10;
        int rem1 = rem & 1023;
        int b = rem1 >> 8;
        int rem2 = rem1 & 255;
        int ct = rem2 >> 6;
        int mt = rem2 & 63;
        const float* src = ((v == 0) ? x0 : x1) + (long long)b * CC * HW
                           + (long long)(ct * 32) * HW + mt * 64;
#pragma unroll
        for (int it = 0; it < 2; it++) {
            int c = tid >> 3, x4 = (tid & 7) + it * 8;
            float4 w = *(const float4*)(src + (long long)c * HW + x4 * 4);
            ld2[c][x4 * 4 + 0] = w.x;
            ld2[c][x4 * 4 + 1] = w.y;
            ld2[c][x4 * 4 + 2] = w.z;
            ld2[c][x4 * 4 + 3] = w.w;
        }
        __syncthreads();
        int m = tid >> 2, cg = tid & 3;
        union { unsigned u[4]; } pk;
#pragma unroll
        for (int t = 0; t < 4; t++) {
            unsigned short h0 = f2bf(ld2[cg * 8 + 2 * t][m]);
            unsigned short h1 = f2bf(ld2[cg * 8 + 2 * t + 1][m]);
            pk.u[t] = (unsigned)h0 | ((unsigned)h1 << 16);
        }
        *(uint4*)(xT + (((long long)(v * 4 + b)) * HW + mt * 64 + m) * 128
                  + ct * 32 + cg * 8) = *(uint4*)pk.u;
    }
}

// ---------------------------------------------------------------------------
// K4) fused sample + K/V conv (MFMA), clamped-base bilinear (NaN-safe).
__global__ __launch_bounds__(256) void sample_kv(const unsigned short* __restrict__ xT,
                                                 const float* __restrict__ posb,
                                                 const unsigned short* __restrict__ wkh,
                                                 const unsigned short* __restrict__ wvh,
                                                 const float* __restrict__ bk,
                                                 const float* __restrict__ bv,
                                                 unsigned short* __restrict__ kbf,
                                                 unsigned short* __restrict__ vbf) {
    __shared__ unsigned short xls[32 * 128];      // 8 KB, XOR-swizzled rows
    int blk = blockIdx.x;                 // 96
    int pb = blk >> 3;
    int nt = blk & 7;
    int p = pb >> 2, b = pb & 3;
    int n0 = nt * 32;
    int tid = threadIdx.x;

    {
        int nl = tid >> 3, co = tid & 7;
        int n = n0 + nl;
        float py = posb[(pb * 256 + n) * 2 + 0];
        float px = posb[(pb * 256 + n) * 2 + 1];
        float yi = (py + 1.f) * 31.5f, xi = (px + 1.f) * 31.5f;
        yi = fminf(fmaxf(yi, 0.f), 63.f);
        xi = fminf(fmaxf(xi, 0.f), 63.f);
        int y0 = min((int)yi, 62);
        int x0i = min((int)xi, 62);
        float wy = yi - (float)y0, wx = xi - (float)x0i;
        float w00 = (1.f - wy) * (1.f - wx), w01 = (1.f - wy) * wx;
        float w10 = wy * (1.f - wx), w11 = wy * wx;
        int vsel = (p == 2) ? 1 : 0;
        const unsigned short* base = xT + ((long long)(vsel * 4 + b)) * HW * 128;
        int m00 = y0 * 64 + x0i;
        char* dst = (char*)xls;
#pragma unroll
        for (int cb = 0; cb < 2; cb++) {
            int c0 = co * 16 + cb * 8;
            bf16x8 a = *(const bf16x8*)(base + (long long)m00 * 128 + c0);
            bf16x8 bb = *(const bf16x8*)(base + (long long)(m00 + 1) * 128 + c0);
            bf16x8 cc = *(const bf16x8*)(base + (long long)(m00 + 64) * 128 + c0);
            bf16x8 dd = *(const bf16x8*)(base + (long long)(m00 + 65) * 128 + c0);
            union { unsigned u[4]; bf16x8 v; } R;
#pragma unroll
            for (int t = 0; t < 4; t++) {
                float r0 = w00 * bflo((unsigned)(unsigned short)a[2 * t])
                         + w01 * bflo((unsigned)(unsigned short)bb[2 * t])
                         + w10 * bflo((unsigned)(unsigned short)cc[2 * t])
                         + w11 * bflo((unsigned)(unsigned short)dd[2 * t]);
                float r1 = w00 * bflo((unsigned)(unsigned short)a[2 * t + 1])
                         + w01 * bflo((unsigned)(unsigned short)bb[2 * t + 1])
                         + w10 * bflo((unsigned)(unsigned short)cc[2 * t + 1])
                         + w11 * bflo((unsigned)(unsigned short)dd[2 * t + 1]);
                R.u[t] = (unsigned)f2bf(r0) | ((unsigned)f2bf(r1) << 16);
            }
            *(bf16x8*)(dst + ((nl * 256 + c0 * 2) ^ ((nl & 7) << 4))) = R.v;
        }
    }
    __syncthreads();

    int wid = tid >> 6, lane = tid & 63;
    int g = lane >> 4, lm = lane & 15;
    int ntile = wid & 1, isv = wid >> 1;
    int nl = ntile * 16 + lm;
    const char* srcl = (const char*)xls;
    bf16x8 xf[4];
#pragma unroll
    for (int ks = 0; ks < 4; ks++)
        xf[ks] = *(const bf16x8*)(srcl + ((nl * 256 + (ks * 32 + 8 * g) * 2)
                                          ^ ((nl & 7) << 4)));
    f32x4 zero = {0.f, 0.f, 0.f, 0.f};
    if (!isv) {
        const unsigned short* WK = wkh + p * 16384;
#pragma unroll
        for (int ct = 0; ct < 8; ct++) {
            f32x4 acc = zero;
#pragma unroll
            for (int ks = 0; ks < 4; ks++) {
                bf16x8 wf = *(const bf16x8*)(WK + (ct * 16 + lm) * 128 + ks * 32 + 8 * g);
                acc = __builtin_amdgcn_mfma_f32_16x16x32_bf16(xf[ks], wf, acc, 0, 0, 0);
            }
            float bias = bk[p * 128 + ct * 16 + lm];
#pragma unroll
            for (int r = 0; r < 4; r++) {
                int n = n0 + ntile * 16 + 4 * g + r;
                kbf[((long long)pb * 256 + n) * 128 + ct * 16 + lm] = f2bf(acc[r] + bias);
            }
        }
    } else {
        const unsigned short* WV = wvh + p * 16384;
#pragma unroll
        for (int ct = 0; ct < 8; ct++) {
            f32x4 acc = zero;
#pragma unroll
            for (int ks = 0; ks < 4; ks++) {
                bf16x8 wf = *(const bf16x8*)(WV + (ct * 16 + lm) * 128 + ks * 32 + 8 * g);
                acc = __builtin_amdgcn_mfma_f32_16x16x32_bf16(wf, xf[ks], acc, 0, 0, 0);
            }
#pragma unroll
            for (int r = 0; r < 4; r++) {
                int c = ct * 16 + 4 * g + r;
                vbf[((long long)pb * 128 + c) * 256 + n0 + ntile * 16 + lm]
                    = f2bf(acc[r] + bv[p * 128 + c]);
            }
        }
    }
}

// ---------------------------------------------------------------------------
// K5) MFMA attention. Bias via alignbyte + packed-bf16 dot2 from LDS table.
__global__ __launch_bounds__(256, 4) void attn_mfma(
        const unsigned short* __restrict__ qbf,
        const unsigned short* __restrict__ kbf,
        const unsigned short* __restrict__ vbf,
        const unsigned short* __restrict__ tabbf,
        const uint4* __restrict__ prmb,
        float* __restrict__ obuf) {
    __shared__ unsigned short tab[16384 + 8];   // +8: speculative dword pad
    __shared__ uint4 prm[256];
    int tid = threadIdx.x;
    int wid = tid >> 6, lane = tid & 63;
    int g = lane >> 4, lm = lane & 15;
    int bid = blockIdx.x;                     // 3072
    int my = bid & 63;
    int h = (bid >> 6) & 3;
    int b = (bid >> 8) & 3;
    int p = bid >> 10;
    int pb = p * 4 + b;

    {   // stage table + params
        const uint4* ts = (const uint4*)(tabbf + (long long)(p * 4 + h) * 16384);
        uint4* td = (uint4*)tab;
#pragma unroll
        for (int i = 0; i < 8; i++) td[tid + i * 256] = ts[tid + i * 256];
        prm[tid] = prmb[pb * 256 + tid];
    }
    __syncthreads();

    int mx = (wid << 4) + lm;

    // ---- QK^T (swapped): A = K[n][c], B = Q^T[c][m]; q pre-scaled ----
    bf16x8 qf = *(const bf16x8*)(qbf + ((long long)pb * HW + my * 64 + mx) * 128
                                 + h * 32 + 8 * g);
    const unsigned short* kbase = kbf + ((long long)pb * 256 + lm) * 128
                                  + h * 32 + 8 * g;
    f32x4 zero = {0.f, 0.f, 0.f, 0.f};
    f32x4 acc[16];
    __builtin_amdgcn_s_setprio(1);
#pragma unroll
    for (int ni = 0; ni < 16; ni++) {
        bf16x8 kf = *(const bf16x8*)(kbase + ni * 16 * 128);
        acc[ni] = __builtin_amdgcn_mfma_f32_16x16x32_bf16(kf, qf, zero, 0, 0, 0);
    }
    __builtin_amdgcn_s_setprio(0);

    // ---- RPE bias: aligned b32 pair reads + alignbyte + dot2 ----
    int laneoff = (my * 128 + mx) * 2;
    const char* tb = (const char*)tab;
#pragma unroll
    for (int ni = 0; ni < 16; ni++) {
#pragma unroll
        for (int r = 0; r < 4; r++) {
            int n = ni * 16 + 4 * g + r;
            uint4 pw = prm[n];
            int va = (int)pw.z + laneoff;
            int va4 = va & ~3;
            int sh = va & 3;
            unsigned r0 = *(const unsigned*)(tb + va4);
            unsigned r1 = *(const unsigned*)(tb + va4 + 4);
            unsigned r2 = *(const unsigned*)(tb + va4 + 256);
            unsigned r3 = *(const unsigned*)(tb + va4 + 260);
            unsigned p0 = __builtin_amdgcn_alignbyte(r1, r0, sh);
            unsigned p1 = __builtin_amdgcn_alignbyte(r3, r2, sh);
            float t = acc[ni][r];
            t = dot2bf(p0, pw.x, t);
            t = dot2bf(p1, pw.y, t);
            acc[ni][r] = t;
        }
    }

    // ---- softmax over n ----
    float mxv = -1e30f;
#pragma unroll
    for (int ni = 0; ni < 16; ni++)
        mxv = fmaxf(mxv, fmaxf(fmaxf(acc[ni][0], acc[ni][1]),
                               fmaxf(acc[ni][2], acc[ni][3])));
    mxv = fmaxf(mxv, __shfl_xor(mxv, 16));
    mxv = fmaxf(mxv, __shfl_xor(mxv, 32));
    float sum = 0.f;
    unsigned dwA[16], dwB[16];
#pragma unroll
    for (int ni = 0; ni < 16; ni++) {
        float e0 = __expf(acc[ni][0] - mxv);
        float e1 = __expf(acc[ni][1] - mxv);
        float e2 = __expf(acc[ni][2] - mxv);
        float e3 = __expf(acc[ni][3] - mxv);
        sum += (e0 + e1) + (e2 + e3);
        asm("v_cvt_pk_bf16_f32 %0, %1, %2" : "=v"(dwA[ni]) : "v"(e0), "v"(e1));
        asm("v_cvt_pk_bf16_f32 %0, %1, %2" : "=v"(dwB[ni]) : "v"(e2), "v"(e3));
    }
    sum += __shfl_xor(sum, 16);
    sum += __shfl_xor(sum, 32);

    // ---- PV: pf assembled via shfl exchange ----
    int src0 = ((g & 1) << 5) + lm;
    int src1 = src0 + 16;
    bool sel = (g >> 1) != 0;
    const unsigned short* vb0 = vbf + ((long long)pb * 128 + h * 32 + lm) * 256
                                + 8 * g;
    f32x4 o0 = zero, o1 = zero;
#pragma unroll
    for (int st = 0; st < 8; st++) {
        unsigned d0a = __shfl(dwA[2 * st], src0), d0b = __shfl(dwA[2 * st + 1], src0);
        unsigned d1a = __shfl(dwB[2 * st], src0), d1b = __shfl(dwB[2 * st + 1], src0);
        unsigned d2a = __shfl(dwA[2 * st], src1), d2b = __shfl(dwA[2 * st + 1], src1);
        unsigned d3a = __shfl(dwB[2 * st], src1), d3b = __shfl(dwB[2 * st + 1], src1);
        union { unsigned u[4]; bf16x8 v; } pf;
        pf.u[0] = sel ? d0b : d0a;
        pf.u[1] = sel ? d1b : d1a;
        pf.u[2] = sel ? d2b : d2a;
        pf.u[3] = sel ? d3b : d3a;
        bf16x8 v0 = *(const bf16x8*)(vb0 + st * 32);
        bf16x8 v1 = *(const bf16x8*)(vb0 + 4096 + st * 32);
        __builtin_amdgcn_s_setprio(1);
        o0 = __builtin_amdgcn_mfma_f32_16x16x32_bf16(v0, pf.v, o0, 0, 0, 0);
        o1 = __builtin_amdgcn_mfma_f32_16x16x32_bf16(v1, pf.v, o1, 0, 0, 0);
        __builtin_amdgcn_s_setprio(0);
    }

    float inv = 1.f / sum;
    float* ob = obuf + ((long long)pb * 128 + h * 32) * HW + my * 64 + mx;
#pragma unroll
    for (int r = 0; r < 4; r++) {
        ob[(g * 4 + r) * HW] = o0[r] * inv;
        ob[(16 + g * 4 + r) * HW] = o1[r] * inv;
    }
}

// ---------------------------------------------------------------------------
// K6) conv_wo via MFMA (bf16): out = x + sum_p Wo[p] o[p] + bo on chans
//     128:256 of vars 1,2.
__global__ __launch_bounds__(256) void conv_wo(const float* __restrict__ x1,
                                               const float* __restrict__ x2,
                                               const float* __restrict__ obuf,
                                               const unsigned short* __restrict__ woh,
                                               const float* __restrict__ bo,
                                               float* __restrict__ out) {
    int wid = threadIdx.x >> 6, lane = threadIdx.x & 63;
    int g = lane >> 4, lm = lane & 15;
    int gw = blockIdx.x * 4 + wid;            // 2048 waves
    int mt = gw & 255;
    int b = (gw >> 8) & 3;
    int vs = gw >> 10;
    int m = mt * 16 + lm;
    int np = vs + 1;

    f32x4 acc[8];
#pragma unroll
    for (int ct = 0; ct < 8; ct++) acc[ct] = (f32x4){0.f, 0.f, 0.f, 0.f};

    for (int pi = 0; pi < np; pi++) {
        int p = vs ? (1 + pi) : 0;
        const float* O = obuf + (long long)(p * 4 + b) * 128 * HW;
        bf16x8 bh[4];
#pragma unroll
        for (int ksl = 0; ksl < 4; ksl++) {
            float v[8];
#pragma unroll
            for (int j = 0; j < 8; j++)
                v[j] = O[(long long)(ksl * 32 + 8 * g + j) * HW + m];
            union { unsigned u[4]; bf16x8 v; } H;
#pragma unroll
            for (int t = 0; t < 4; t++)
                H.u[t] = (unsigned)f2bf(v[2 * t]) | ((unsigned)f2bf(v[2 * t + 1]) << 16);
            bh[ksl] = H.v;
        }
        const unsigned short* WH = woh + p * 16384;
#pragma unroll
        for (int ct = 0; ct < 8; ct++)
#pragma unroll
            for (int ksl = 0; ksl < 4; ksl++) {
                bf16x8 A = *(const bf16x8*)(WH + (ct * 16 + lm) * 128 + ksl * 32 + 8 * g);
                acc[ct] = __builtin_amdgcn_mfma_f32_16x16x32_bf16(A, bh[ksl], acc[ct], 0, 0, 0);
            }
    }

    int qi = vs + 1;
    const float* xq = (vs ? x2 : x1) + (long long)b * CC * HW;
#pragma unroll
    for (int ct = 0; ct < 8; ct++)
#pragma unroll
        for (int r = 0; r < 4; r++) {
            int c = ct * 16 + 4 * g + r;
            float bias = vs ? (bo[128 + c] + bo[256 + c]) : bo[c];
            float base = xq[(long long)(128 + c) * HW + m];
            out[(((long long)(qi * 4 + b)) * CC + 128 + c) * HW + m]
                = base + acc[ct][r] + bias;
        }
}

// ---------------------------------------------------------------------------
extern "C" void kernel_launch(void* const* d_in, const int* in_sizes, int n_in,
                              void* d_out, int out_size, void* d_ws, size_t ws_size,
                              hipStream_t stream) {
    const float* x0 = (const float*)d_in[0];
    const float* x1 = (const float*)d_in[1];
    const float* x2 = (const float*)d_in[2];
    const float* Wq = (const float*)d_in[3];
    const float* bq = (const float*)d_in[4];
    const float* Wk = (const float*)d_in[5];
    const float* bk = (const float*)d_in[6];
    const float* Wv = (const float*)d_in[7];
    const float* bv = (const float*)d_in[8];
    const float* Wo = (const float*)d_in[9];
    const float* bo = (const float*)d_in[10];
    const float* dw_w = (const float*)d_in[11];
    const float* dw_b = (const float*)d_in[12];
    const float* ln_g = (const float*)d_in[13];
    const float* ln_b = (const float*)d_in[14];
    const float* pw_w = (const float*)d_in[15];
    const float* rpe = (const float*)d_in[16];
    float* out = (float*)d_out;

    // Region A: qbuf f32 (K2 w, K3 r) -> obuf f32 (K5 w, K6 r), disjoint.
    // xT is now NON-aliased (K3 writes it while other K3 blocks read qbuf).
    float* ws = (float*)d_ws;
    float* qbuf = ws;                                   // 6291456 f (24 MB)
    float* obuf = qbuf;                                 // alias (disjoint lifetime)
    float* posb = ws + 6291456;                         // 6144 f
    unsigned short* xT = (unsigned short*)(posb + 6144);     // 4194304 s (8 MB)
    unsigned short* qbf = xT + 4194304;                      // 12582912 s (24 MB)
    unsigned short* kbf = qbf + 12582912;                    // 393216 s
    unsigned short* vbf = kbf + 393216;                      // 393216 s
    unsigned short* tabbf = vbf + 393216;                    // 196608 s
    uint4* prmb = (uint4*)(tabbf + 196608);                  // 3072 uint4
    unsigned short* wqh = (unsigned short*)(prmb + 3072);    // 49152 s
    unsigned short* wql = wqh + 49152;
    unsigned short* woh = wql + 49152;
    unsigned short* wkh = woh + 49152;
    unsigned short* wvh = wkh + 49152;
    // total ~ 59 MB

    prep_copy<<<1048, 256, 0, stream>>>(rpe, Wq, Wo, Wk, Wv, x0, tabbf,
                                        wqh, wql, woh, wkh, wvh, out);
    conv_q<<<768, 256, 0, stream>>>(x1, x2, wqh, wql, bq, qbuf, qbf, out);
    mid_kernel<<<2240, 256, 0, stream>>>(qbuf, dw_w, dw_b, ln_g, ln_b, pw_w,
                                         x0, x1, posb, prmb, xT);
    sample_kv<<<96, 256, 0, stream>>>(xT, posb, wkh, wvh, bk, bv, kbf, vbf);
    attn_mfma<<<3072, 256, 0, stream>>>(qbf, kbf, vbf, tabbf, prmb, obuf);
    conv_wo<<<512, 256, 0, stream>>>(x1, x2, obuf, woh, bo, out);
}

// Round 10
// 181.115 us; speedup vs baseline: 2.0089x; 1.0027x over previous
//
#include <hip/hip_runtime.h>
#include <math.h>

// Problem constants
#define NVAR 3
#define BB 4
#define CC 256
#define C1 128
#define HEADS 4
#define HH 64
#define WW 64
#define HW 4096
#define RPE_W 127
#define NP 3
#define SCALE 0.17677669529663687f
// pairs: p=0 -> (i=1,j=0), p=1 -> (i=2,j=0), p=2 -> (i=2,j=1)

typedef short bf16x8 __attribute__((ext_vector_type(8)));
typedef float f32x4 __attribute__((ext_vector_type(4)));
typedef __bf16 bf16x2 __attribute__((ext_vector_type(2)));

__device__ __forceinline__ unsigned short f2bf(float f) {
    unsigned int u = __float_as_uint(f);
    u += 0x7fffu + ((u >> 16) & 1u);          // round-to-nearest-even
    return (unsigned short)(u >> 16);
}
__device__ __forceinline__ float bflo(unsigned u) { return __uint_as_float(u << 16); }
__device__ __forceinline__ float bfhi(unsigned u) { return __uint_as_float(u & 0xffff0000u); }

// packed bf16x2 dot: c + a.lo*b.lo + a.hi*b.hi
__device__ __forceinline__ float dot2bf(unsigned a, unsigned b, float c) {
#if __has_builtin(__builtin_amdgcn_fdot2_f32_bf16)
    return __builtin_amdgcn_fdot2_f32_bf16(__builtin_bit_cast(bf16x2, a),
                                           __builtin_bit_cast(bf16x2, b), c, false);
#else
    return c + bflo(a) * bflo(b) + bfhi(a) * bfhi(b);
#endif
}

// ---------------------------------------------------------------------------
// K1) const prep (blocks 0..23) + copy x0 -> out var0 + flow zeros (24..1047)
__global__ __launch_bounds__(256) void prep_copy(const float* __restrict__ rpe,
                                                 const float* __restrict__ Wq,
                                                 const float* __restrict__ Wo,
                                                 const float* __restrict__ Wk,
                                                 const float* __restrict__ Wv,
                                                 const float* __restrict__ x0,
                                                 unsigned short* __restrict__ tabbf,
                                                 unsigned short* __restrict__ wqh,
                                                 unsigned short* __restrict__ wql,
                                                 unsigned short* __restrict__ woh,
                                                 unsigned short* __restrict__ wkh,
                                                 unsigned short* __restrict__ wvh,
                                                 float* __restrict__ out) {
    int blk = blockIdx.x;
    if (blk >= 24) {
        const long long n4 = (long long)BB * CC * HW / 4;
        long long i = (long long)(blk - 24) * 256 + threadIdx.x;
        const long long stride = 1024LL * 256;
        for (; i < n4 + 12; i += stride) {
            if (i < n4) ((float4*)out)[i] = ((const float4*)x0)[i];
            else out[3LL * BB * CC * HW + (i - n4)] = 0.f;
        }
        return;
    }
    if (blk < 12) {
        const float* src = rpe + (long long)blk * RPE_W * RPE_W;
        unsigned short* dst = tabbf + (long long)blk * 16384;
        for (int idx = threadIdx.x; idx < 16384; idx += 256) {
            int y = idx >> 7, x = idx & 127;
            float v = (y < RPE_W && x < RPE_W) ? src[y * RPE_W + x] : 0.f;
            dst[idx] = f2bf(v);
        }
    } else if (blk < 15) {
        int p = blk - 12;
        for (int i = threadIdx.x; i < 16384; i += 256) {
            float w = Wq[p * 16384 + i];
            unsigned short h = f2bf(w);
            wqh[p * 16384 + i] = h;
            wql[p * 16384 + i] = f2bf(w - bflo((unsigned)h));
        }
    } else if (blk < 18) {
        int p = blk - 15;
        for (int i = threadIdx.x; i < 16384; i += 256)
            woh[p * 16384 + i] = f2bf(Wo[p * 16384 + i]);
    } else if (blk < 21) {
        int p = blk - 18;
        for (int i = threadIdx.x; i < 16384; i += 256)
            wkh[p * 16384 + i] = f2bf(Wk[p * 16384 + i]);
    } else {
        int p = blk - 21;
        for (int i = threadIdx.x; i < 16384; i += 256)
            wvh[p * 16384 + i] = f2bf(Wv[p * 16384 + i]);
    }
}

// ---------------------------------------------------------------------------
// K2) conv_q via MFMA, split bf16 (hi+lo). Outputs qbuf f32 [pb][c][m],
//     qbf bf16 [pb][m][c] (pre-scaled, coalesced via LDS bounce), AND copies
//     x chans 0:128 into out.
__global__ __launch_bounds__(256) void conv_q(const float* __restrict__ x1,
                                              const float* __restrict__ x2,
                                              const unsigned short* __restrict__ wqh,
                                              const unsigned short* __restrict__ wql,
                                              const float* __restrict__ bq,
                                              float* __restrict__ qbuf,
                                              unsigned short* __restrict__ qbf,
                                              float* __restrict__ out) {
    __shared__ unsigned short qlds[4][16][136];   // 17 KB; 16B-aligned rows
    int wid = threadIdx.x >> 6, lane = threadIdx.x & 63;
    int g = lane >> 4, lm = lane & 15;
    int gw = blockIdx.x * 4 + wid;            // 3072 waves
    int mt = gw & 255;
    int pb = gw >> 8;
    int p = pb >> 2, b = pb & 3;
    const float* X = ((p == 0) ? x1 : x2) + (long long)b * CC * HW;
    int m = mt * 16 + lm;
    float* outc = (p < 2)
        ? out + (((long long)((p + 1) * 4 + b)) * CC) * HW + m
        : nullptr;

    bf16x8 bhi[4], blo[4];
#pragma unroll
    for (int ksl = 0; ksl < 4; ksl++) {
        float v[8];
#pragma unroll
        for (int j = 0; j < 8; j++) {
            int k = ksl * 32 + 8 * g + j;
            v[j] = X[(long long)k * HW + m];
            if (outc) outc[(long long)k * HW] = v[j];
        }
        union { unsigned u[4]; bf16x8 v; } H, L;
#pragma unroll
        for (int t = 0; t < 4; t++) {
            unsigned short h0 = f2bf(v[2 * t]), h1 = f2bf(v[2 * t + 1]);
            unsigned short l0 = f2bf(v[2 * t] - bflo((unsigned)h0));
            unsigned short l1 = f2bf(v[2 * t + 1] - bflo((unsigned)h1));
            H.u[t] = (unsigned)h0 | ((unsigned)h1 << 16);
            L.u[t] = (unsigned)l0 | ((unsigned)l1 << 16);
        }
        bhi[ksl] = H.v;
        blo[ksl] = L.v;
    }

    const unsigned short* WH = wqh + p * 16384;
    const unsigned short* WL = wql + p * 16384;
    unsigned short* ql = &qlds[wid][lm][0];
    f32x4 zero = {0.f, 0.f, 0.f, 0.f};
#pragma unroll
    for (int ct2 = 0; ct2 < 4; ct2++) {
        int ct0 = 2 * ct2, ct1 = ct0 + 1;
        f32x4 a0 = zero, a1 = zero;
#pragma unroll
        for (int ksl = 0; ksl < 4; ksl++) {
            bf16x8 Ah0 = *(const bf16x8*)(WH + (ct0 * 16 + lm) * 128 + ksl * 32 + 8 * g);
            bf16x8 Al0 = *(const bf16x8*)(WL + (ct0 * 16 + lm) * 128 + ksl * 32 + 8 * g);
            bf16x8 Ah1 = *(const bf16x8*)(WH + (ct1 * 16 + lm) * 128 + ksl * 32 + 8 * g);
            bf16x8 Al1 = *(const bf16x8*)(WL + (ct1 * 16 + lm) * 128 + ksl * 32 + 8 * g);
            a0 = __builtin_amdgcn_mfma_f32_16x16x32_bf16(Ah0, bhi[ksl], a0, 0, 0, 0);
            a1 = __builtin_amdgcn_mfma_f32_16x16x32_bf16(Ah1, bhi[ksl], a1, 0, 0, 0);
            a0 = __builtin_amdgcn_mfma_f32_16x16x32_bf16(Ah0, blo[ksl], a0, 0, 0, 0);
            a1 = __builtin_amdgcn_mfma_f32_16x16x32_bf16(Ah1, blo[ksl], a1, 0, 0, 0);
            a0 = __builtin_amdgcn_mfma_f32_16x16x32_bf16(Al0, bhi[ksl], a0, 0, 0, 0);
            a1 = __builtin_amdgcn_mfma_f32_16x16x32_bf16(Al1, bhi[ksl], a1, 0, 0, 0);
        }
        float q0[4], q1[4];
#pragma unroll
        for (int r = 0; r < 4; r++) {
            int c0 = ct0 * 16 + 4 * g + r, c1 = ct1 * 16 + 4 * g + r;
            q0[r] = a0[r] + bq[p * 128 + c0];
            q1[r] = a1[r] + bq[p * 128 + c1];
            qbuf[((long long)pb * 128 + c0) * HW + m] = q0[r];
            qbuf[((long long)pb * 128 + c1) * HW + m] = q1[r];
        }
        *(unsigned*)(ql + ct0 * 16 + 4 * g) =
            (unsigned)f2bf(q0[0] * SCALE) | ((unsigned)f2bf(q0[1] * SCALE) << 16);
        *(unsigned*)(ql + ct0 * 16 + 4 * g + 2) =
            (unsigned)f2bf(q0[2] * SCALE) | ((unsigned)f2bf(q0[3] * SCALE) << 16);
        *(unsigned*)(ql + ct1 * 16 + 4 * g) =
            (unsigned)f2bf(q1[0] * SCALE) | ((unsigned)f2bf(q1[1] * SCALE) << 16);
        *(unsigned*)(ql + ct1 * 16 + 4 * g + 2) =
            (unsigned)f2bf(q1[2] * SCALE) | ((unsigned)f2bf(q1[3] * SCALE) << 16);
    }

    // same-wave LDS readback -> coalesced 1KB-contiguous global stores
    unsigned short* Yb = qbf + ((long long)pb * HW + mt * 16) * 128;
    int q = lane >> 4, cg = lane & 15;
#pragma unroll
    for (int i = 0; i < 4; i++) {
        int row = i * 4 + q;
        uint4 vv = *(const uint4*)&qlds[wid][row][cg * 8];
        *(uint4*)(Yb + row * 128 + cg * 8) = vv;
    }
}

// ---------------------------------------------------------------------------
// K3) fused middle kernel:
//   blocks 0..191:  offset net (depthwise conv staged in LDS -> LN -> GELU ->
//                   1x1 -> pos + prm), per (pb,hk); 'off' never leaves LDS.
//   blocks 192..2239: transpose x0,x1 chans 0:128 -> xT bf16 [v][b][m][c].
__global__ __launch_bounds__(256) void mid_kernel(const float* __restrict__ qbuf,
                                                  const float* __restrict__ dw_w,
                                                  const float* __restrict__ dw_b,
                                                  const float* __restrict__ ln_g,
                                                  const float* __restrict__ ln_b,
                                                  const float* __restrict__ pw_w,
                                                  const float* __restrict__ x0,
                                                  const float* __restrict__ x1,
                                                  float* __restrict__ posb,
                                                  uint4* __restrict__ prmb,
                                                  unsigned short* __restrict__ xT) {
    __shared__ float sm[32 * 4 * 65 + 16 * 128];     // 41.5 KB
    int blk = blockIdx.x;
    int tid = threadIdx.x;
    if (blk < 192) {
        float (*ld)[4][65] = (float(*)[4][65])sm;
        float (*dwout)[128] = (float(*)[128])(sm + 32 * 4 * 65);
        int pb = blk >> 4, hk = blk & 15;
        int p = pb >> 2;
        for (int cq = 0; cq < 4; cq++) {
            int c32 = cq * 32;
            __syncthreads();
#pragma unroll
            for (int it = 0; it < 8; it++) {
                int i2 = tid + it * 256;          // 2048 float4
                int c = i2 >> 6, rem = i2 & 63;
                int y = rem >> 4, xq = rem & 15;
                float4 v = *(const float4*)(qbuf + ((long long)pb * 128 + c32 + c) * HW
                                            + (4 * hk + y) * 64 + xq * 4);
                ld[c][y][xq * 4 + 0] = v.x;
                ld[c][y][xq * 4 + 1] = v.y;
                ld[c][y][xq * 4 + 2] = v.z;
                ld[c][y][xq * 4 + 3] = v.w;
            }
            __syncthreads();
            int wk = tid >> 4;
#pragma unroll
            for (int oi = 0; oi < 2; oi++) {
                int c = (tid & 15) + oi * 16;
                const float* dwp = dw_w + (p * 128 + c32 + c) * 16;
                float acc = dw_b[p * 128 + c32 + c];
#pragma unroll
                for (int ky = 0; ky < 4; ky++)
#pragma unroll
                    for (int kx = 0; kx < 4; kx++)
                        acc += ld[c][ky][wk * 4 + kx] * dwp[ky * 4 + kx];
                dwout[wk][c32 + c] = acc;
            }
        }
        __syncthreads();
        // LN phase: 4 waves x 4 wk each
        int wid = tid >> 6, lane = tid & 63;
        for (int i = 0; i < 4; i++) {
            int wk = wid * 4 + i;
            int s = hk * 16 + wk;
            float a0 = dwout[wk][lane], a1 = dwout[wk][lane + 64];
            float s1 = a0 + a1;
#pragma unroll
            for (int o = 1; o < 64; o <<= 1) s1 += __shfl_xor(s1, o);
            float mu = s1 * (1.f / 128.f);
            float d0 = a0 - mu, d1 = a1 - mu;
            float v2 = d0 * d0 + d1 * d1;
#pragma unroll
            for (int o = 1; o < 64; o <<= 1) v2 += __shfl_xor(v2, o);
            float rs = rsqrtf(v2 * (1.f / 128.f) + 1e-5f);
            int c0 = lane, c1 = lane + 64;
            float y0 = d0 * rs * ln_g[p * 128 + c0] + ln_b[p * 128 + c0];
            float y1 = d1 * rs * ln_g[p * 128 + c1] + ln_b[p * 128 + c1];
            float g0 = 0.5f * y0 * (1.f + erff(y0 * 0.70710678118654752f));
            float g1 = 0.5f * y1 * (1.f + erff(y1 * 0.70710678118654752f));
            float o0 = pw_w[(p * 2 + 0) * 128 + c0] * g0
                     + pw_w[(p * 2 + 0) * 128 + c1] * g1;
            float o1 = pw_w[(p * 2 + 1) * 128 + c0] * g0
                     + pw_w[(p * 2 + 1) * 128 + c1] * g1;
#pragma unroll
            for (int o = 1; o < 64; o <<= 1) o0 += __shfl_xor(o0, o);
#pragma unroll
            for (int o = 1; o < 64; o <<= 1) o1 += __shfl_xor(o1, o);
            if (lane == 0) {
                int wk2 = s & 15;
                float refy = (hk + 0.5f) * (2.f / 15.f) - 1.f;
                float refx = (wk2 + 0.5f) * (2.f / 15.f) - 1.f;
                float py = fminf(fmaxf(o0 + refy, -1.f), 1.f);
                float px = fminf(fmaxf(o1 + refx, -1.f), 1.f);
                int pbn = pb * 256 + s;
                posb[pbn * 2 + 0] = py;
                posb[pbn * 2 + 1] = px;
                float cy = 31.5f * (1.f - py), cx = 31.5f * (1.f - px);
                float yf = floorf(cy), xf = floorf(cx);
                float wy = cy - yf, wx = cx - xf;
                int Y0 = (int)yf, X0 = (int)xf;
                uint4 v;
                v.x = (unsigned)f2bf((1.f - wy) * (1.f - wx))
                    | ((unsigned)f2bf((1.f - wy) * wx) << 16);
                v.y = (unsigned)f2bf(wy * (1.f - wx))
                    | ((unsigned)f2bf(wy * wx) << 16);
                v.z = (unsigned)((Y0 * 128 + X0) * 2);
                v.w = 0;
                prmb[pbn] = v;
            }
        }
    } else {
        // transpose part
        float (*ld2)[65] = (float(*)[65])sm;
        int rem = blk - 192;                  // 0..2047
        int v = rem >> 10;
        int rem1 = rem & 1023;
        int b = rem1 >> 8;
        int rem2 = rem1 & 255;
        int ct = rem2 >> 6;
        int mt = rem2 & 63;
        const float* src = ((v == 0) ? x0 : x1) + (long long)b * CC * HW
                           + (long long)(ct * 32) * HW + mt * 64;
#pragma unroll
        for (int it = 0; it < 2; it++) {
            int c = tid >> 3, x4 = (tid & 7) + it * 8;
            float4 w = *(const float4*)(src + (long long)c * HW + x4 * 4);
            ld2[c][x4 * 4 + 0] = w.x;
            ld2[c][x4 * 4 + 1] = w.y;
            ld2[c][x4 * 4 + 2] = w.z;
            ld2[c][x4 * 4 + 3] = w.w;
        }
        __syncthreads();
        int m = tid >> 2, cg = tid & 3;
        union { unsigned u[4]; } pk;
#pragma unroll
        for (int t = 0; t < 4; t++) {
            unsigned short h0 = f2bf(ld2[cg * 8 + 2 * t][m]);
            unsigned short h1 = f2bf(ld2[cg * 8 + 2 * t + 1][m]);
            pk.u[t] = (unsigned)h0 | ((unsigned)h1 << 16);
        }
        *(uint4*)(xT + (((long long)(v * 4 + b)) * HW + mt * 64 + m) * 128
                  + ct * 32 + cg * 8) = *(uint4*)pk.u;
    }
}

// ---------------------------------------------------------------------------
// K4) fused sample + K/V conv (MFMA), clamped-base bilinear (NaN-safe).
__global__ __launch_bounds__(256) void sample_kv(const unsigned short* __restrict__ xT,
                                                 const float* __restrict__ posb,
                                                 const unsigned short* __restrict__ wkh,
                                                 const unsigned short* __restrict__ wvh,
                                                 const float* __restrict__ bk,
                                                 const float* __restrict__ bv,
                                                 unsigned short* __restrict__ kbf,
                                                 unsigned short* __restrict__ vbf) {
    __shared__ unsigned short xls[32 * 128];      // 8 KB, XOR-swizzled rows
    int blk = blockIdx.x;                 // 96
    int pb = blk >> 3;
    int nt = blk & 7;
    int p = pb >> 2, b = pb & 3;
    int n0 = nt * 32;
    int tid = threadIdx.x;

    {
        int nl = tid >> 3, co = tid & 7;
        int n = n0 + nl;
        float py = posb[(pb * 256 + n) * 2 + 0];
        float px = posb[(pb * 256 + n) * 2 + 1];
        float yi = (py + 1.f) * 31.5f, xi = (px + 1.f) * 31.5f;
        yi = fminf(fmaxf(yi, 0.f), 63.f);
        xi = fminf(fmaxf(xi, 0.f), 63.f);
        int y0 = min((int)yi, 62);
        int x0i = min((int)xi, 62);
        float wy = yi - (float)y0, wx = xi - (float)x0i;
        float w00 = (1.f - wy) * (1.f - wx), w01 = (1.f - wy) * wx;
        float w10 = wy * (1.f - wx), w11 = wy * wx;
        int vsel = (p == 2) ? 1 : 0;
        const unsigned short* base = xT + ((long long)(vsel * 4 + b)) * HW * 128;
        int m00 = y0 * 64 + x0i;
        char* dst = (char*)xls;
#pragma unroll
        for (int cb = 0; cb < 2; cb++) {
            int c0 = co * 16 + cb * 8;
            bf16x8 a = *(const bf16x8*)(base + (long long)m00 * 128 + c0);
            bf16x8 bb = *(const bf16x8*)(base + (long long)(m00 + 1) * 128 + c0);
            bf16x8 cc = *(const bf16x8*)(base + (long long)(m00 + 64) * 128 + c0);
            bf16x8 dd = *(const bf16x8*)(base + (long long)(m00 + 65) * 128 + c0);
            union { unsigned u[4]; bf16x8 v; } R;
#pragma unroll
            for (int t = 0; t < 4; t++) {
                float r0 = w00 * bflo((unsigned)(unsigned short)a[2 * t])
                         + w01 * bflo((unsigned)(unsigned short)bb[2 * t])
                         + w10 * bflo((unsigned)(unsigned short)cc[2 * t])
                         + w11 * bflo((unsigned)(unsigned short)dd[2 * t]);
                float r1 = w00 * bflo((unsigned)(unsigned short)a[2 * t + 1])
                         + w01 * bflo((unsigned)(unsigned short)bb[2 * t + 1])
                         + w10 * bflo((unsigned)(unsigned short)cc[2 * t + 1])
                         + w11 * bflo((unsigned)(unsigned short)dd[2 * t + 1]);
                R.u[t] = (unsigned)f2bf(r0) | ((unsigned)f2bf(r1) << 16);
            }
            *(bf16x8*)(dst + ((nl * 256 + c0 * 2) ^ ((nl & 7) << 4))) = R.v;
        }
    }
    __syncthreads();

    int wid = tid >> 6, lane = tid & 63;
    int g = lane >> 4, lm = lane & 15;
    int ntile = wid & 1, isv = wid >> 1;
    int nl = ntile * 16 + lm;
    const char* srcl = (const char*)xls;
    bf16x8 xf[4];
#pragma unroll
    for (int ks = 0; ks < 4; ks++)
        xf[ks] = *(const bf16x8*)(srcl + ((nl * 256 + (ks * 32 + 8 * g) * 2)
                                          ^ ((nl & 7) << 4)));
    f32x4 zero = {0.f, 0.f, 0.f, 0.f};
    if (!isv) {
        const unsigned short* WK = wkh + p * 16384;
#pragma unroll
        for (int ct = 0; ct < 8; ct++) {
            f32x4 acc = zero;
#pragma unroll
            for (int ks = 0; ks < 4; ks++) {
                bf16x8 wf = *(const bf16x8*)(WK + (ct * 16 + lm) * 128 + ks * 32 + 8 * g);
                acc = __builtin_amdgcn_mfma_f32_16x16x32_bf16(xf[ks], wf, acc, 0, 0, 0);
            }
            float bias = bk[p * 128 + ct * 16 + lm];
#pragma unroll
            for (int r = 0; r < 4; r++) {
                int n = n0 + ntile * 16 + 4 * g + r;
                kbf[((long long)pb * 256 + n) * 128 + ct * 16 + lm] = f2bf(acc[r] + bias);
            }
        }
    } else {
        const unsigned short* WV = wvh + p * 16384;
#pragma unroll
        for (int ct = 0; ct < 8; ct++) {
            f32x4 acc = zero;
#pragma unroll
            for (int ks = 0; ks < 4; ks++) {
                bf16x8 wf = *(const bf16x8*)(WV + (ct * 16 + lm) * 128 + ks * 32 + 8 * g);
                acc = __builtin_amdgcn_mfma_f32_16x16x32_bf16(wf, xf[ks], acc, 0, 0, 0);
            }
#pragma unroll
            for (int r = 0; r < 4; r++) {
                int c = ct * 16 + 4 * g + r;
                vbf[((long long)pb * 128 + c) * 256 + n0 + ntile * 16 + lm]
                    = f2bf(acc[r] + bv[p * 128 + c]);
            }
        }
    }
}

// ---------------------------------------------------------------------------
// K5) MFMA attention: 512-thread blocks (8 waves share the 36KB table LDS)
//     -> 4 blocks/CU = 32 waves/CU. VGPR cap 128 via (512,4) — NOT (512,8),
//     which forced VGPR<=64 and spilled (R6 lesson).
__global__ __launch_bounds__(512, 4) void attn_mfma(
        const unsigned short* __restrict__ qbf,
        const unsigned short* __restrict__ kbf,
        const unsigned short* __restrict__ vbf,
        const unsigned short* __restrict__ tabbf,
        const uint4* __restrict__ prmb,
        float* __restrict__ obuf) {
    __shared__ unsigned short tab[16384 + 8];   // +8: speculative dword pad
    __shared__ uint4 prm[256];
    int tid = threadIdx.x;
    int wid = tid >> 6, lane = tid & 63;
    int g = lane >> 4, lm = lane & 15;
    int bid = blockIdx.x;                     // 1536
    int my = ((bid & 31) << 1) + (wid >> 2);
    int h = (bid >> 5) & 3;
    int b = (bid >> 7) & 3;
    int p = bid >> 9;
    int pb = p * 4 + b;

    {   // stage table + params
        const uint4* ts = (const uint4*)(tabbf + (long long)(p * 4 + h) * 16384);
        uint4* td = (uint4*)tab;
#pragma unroll
        for (int i = 0; i < 4; i++) td[tid + i * 512] = ts[tid + i * 512];
        if (tid < 256) prm[tid] = prmb[pb * 256 + tid];
    }
    __syncthreads();

    int mx = ((wid & 3) << 4) + lm;

    // ---- QK^T (swapped): A = K[n][c], B = Q^T[c][m]; q pre-scaled ----
    bf16x8 qf = *(const bf16x8*)(qbf + ((long long)pb * HW + my * 64 + mx) * 128
                                 + h * 32 + 8 * g);
    const unsigned short* kbase = kbf + ((long long)pb * 256 + lm) * 128
                                  + h * 32 + 8 * g;
    f32x4 zero = {0.f, 0.f, 0.f, 0.f};
    f32x4 acc[16];
    __builtin_amdgcn_s_setprio(1);
#pragma unroll
    for (int ni = 0; ni < 16; ni++) {
        bf16x8 kf = *(const bf16x8*)(kbase + ni * 16 * 128);
        acc[ni] = __builtin_amdgcn_mfma_f32_16x16x32_bf16(kf, qf, zero, 0, 0, 0);
    }
    __builtin_amdgcn_s_setprio(0);

    // ---- RPE bias: aligned b32 pair reads + alignbyte + dot2 ----
    int laneoff = (my * 128 + mx) * 2;
    const char* tb = (const char*)tab;
#pragma unroll
    for (int ni = 0; ni < 16; ni++) {
#pragma unroll
        for (int r = 0; r < 4; r++) {
            int n = ni * 16 + 4 * g + r;
            uint4 pw = prm[n];
            int va = (int)pw.z + laneoff;
            int va4 = va & ~3;
            int sh = va & 3;
            unsigned r0 = *(const unsigned*)(tb + va4);
            unsigned r1 = *(const unsigned*)(tb + va4 + 4);
            unsigned r2 = *(const unsigned*)(tb + va4 + 256);
            unsigned r3 = *(const unsigned*)(tb + va4 + 260);
            unsigned p0 = __builtin_amdgcn_alignbyte(r1, r0, sh);
            unsigned p1 = __builtin_amdgcn_alignbyte(r3, r2, sh);
            float t = acc[ni][r];
            t = dot2bf(p0, pw.x, t);
            t = dot2bf(p1, pw.y, t);
            acc[ni][r] = t;
        }
    }

    // ---- softmax over n ----
    float mxv = -1e30f;
#pragma unroll
    for (int ni = 0; ni < 16; ni++)
        mxv = fmaxf(mxv, fmaxf(fmaxf(acc[ni][0], acc[ni][1]),
                               fmaxf(acc[ni][2], acc[ni][3])));
    mxv = fmaxf(mxv, __shfl_xor(mxv, 16));
    mxv = fmaxf(mxv, __shfl_xor(mxv, 32));
    float sum = 0.f;
    unsigned dwA[16], dwB[16];
#pragma unroll
    for (int ni = 0; ni < 16; ni++) {
        float e0 = __expf(acc[ni][0] - mxv);
        float e1 = __expf(acc[ni][1] - mxv);
        float e2 = __expf(acc[ni][2] - mxv);
        float e3 = __expf(acc[ni][3] - mxv);
        sum += (e0 + e1) + (e2 + e3);
        asm("v_cvt_pk_bf16_f32 %0, %1, %2" : "=v"(dwA[ni]) : "v"(e0), "v"(e1));
        asm("v_cvt_pk_bf16_f32 %0, %1, %2" : "=v"(dwB[ni]) : "v"(e2), "v"(e3));
    }
    sum += __shfl_xor(sum, 16);
    sum += __shfl_xor(sum, 32);

    // ---- PV: pf assembled via shfl exchange ----
    int src0 = ((g & 1) << 5) + lm;
    int src1 = src0 + 16;
    bool sel = (g >> 1) != 0;
    const unsigned short* vb0 = vbf + ((long long)pb * 128 + h * 32 + lm) * 256
                                + 8 * g;
    f32x4 o0 = zero, o1 = zero;
#pragma unroll
    for (int st = 0; st < 8; st++) {
        unsigned d0a = __shfl(dwA[2 * st], src0), d0b = __shfl(dwA[2 * st + 1], src0);
        unsigned d1a = __shfl(dwB[2 * st], src0), d1b = __shfl(dwB[2 * st + 1], src0);
        unsigned d2a = __shfl(dwA[2 * st], src1), d2b = __shfl(dwA[2 * st + 1], src1);
        unsigned d3a = __shfl(dwB[2 * st], src1), d3b = __shfl(dwB[2 * st + 1], src1);
        union { unsigned u[4]; bf16x8 v; } pf;
        pf.u[0] = sel ? d0b : d0a;
        pf.u[1] = sel ? d1b : d1a;
        pf.u[2] = sel ? d2b : d2a;
        pf.u[3] = sel ? d3b : d3a;
        bf16x8 v0 = *(const bf16x8*)(vb0 + st * 32);
        bf16x8 v1 = *(const bf16x8*)(vb0 + 4096 + st * 32);
        __builtin_amdgcn_s_setprio(1);
        o0 = __builtin_amdgcn_mfma_f32_16x16x32_bf16(v0, pf.v, o0, 0, 0, 0);
        o1 = __builtin_amdgcn_mfma_f32_16x16x32_bf16(v1, pf.v, o1, 0, 0, 0);
        __builtin_amdgcn_s_setprio(0);
    }

    float inv = 1.f / sum;
    float* ob = obuf + ((long long)pb * 128 + h * 32) * HW + my * 64 + mx;
#pragma unroll
    for (int r = 0; r < 4; r++) {
        ob[(g * 4 + r) * HW] = o0[r] * inv;
        ob[(16 + g * 4 + r) * HW] = o1[r] * inv;
    }
}

// ---------------------------------------------------------------------------
// K6) conv_wo via MFMA (bf16): out = x + sum_p Wo[p] o[p] + bo on chans
//     128:256 of vars 1,2.
__global__ __launch_bounds__(256) void conv_wo(const float* __restrict__ x1,
                                               const float* __restrict__ x2,
                                               const float* __restrict__ obuf,
                                               const unsigned short* __restrict__ woh,
                                               const float* __restrict__ bo,
                                               float* __restrict__ out) {
    int wid = threadIdx.x >> 6, lane = threadIdx.x & 63;
    int g = lane >> 4, lm = lane & 15;
    int gw = blockIdx.x * 4 + wid;            // 2048 waves
    int mt = gw & 255;
    int b = (gw >> 8) & 3;
    int vs = gw >> 10;
    int m = mt * 16 + lm;
    int np = vs + 1;

    f32x4 acc[8];
#pragma unroll
    for (int ct = 0; ct < 8; ct++) acc[ct] = (f32x4){0.f, 0.f, 0.f, 0.f};

    for (int pi = 0; pi < np; pi++) {
        int p = vs ? (1 + pi) : 0;
        const float* O = obuf + (long long)(p * 4 + b) * 128 * HW;
        bf16x8 bh[4];
#pragma unroll
        for (int ksl = 0; ksl < 4; ksl++) {
            float v[8];
#pragma unroll
            for (int j = 0; j < 8; j++)
                v[j] = O[(long long)(ksl * 32 + 8 * g + j) * HW + m];
            union { unsigned u[4]; bf16x8 v; } H;
#pragma unroll
            for (int t = 0; t < 4; t++)
                H.u[t] = (unsigned)f2bf(v[2 * t]) | ((unsigned)f2bf(v[2 * t + 1]) << 16);
            bh[ksl] = H.v;
        }
        const unsigned short* WH = woh + p * 16384;
#pragma unroll
        for (int ct = 0; ct < 8; ct++)
#pragma unroll
            for (int ksl = 0; ksl < 4; ksl++) {
                bf16x8 A = *(const bf16x8*)(WH + (ct * 16 + lm) * 128 + ksl * 32 + 8 * g);
                acc[ct] = __builtin_amdgcn_mfma_f32_16x16x32_bf16(A, bh[ksl], acc[ct], 0, 0, 0);
            }
    }

    int qi = vs + 1;
    const float* xq = (vs ? x2 : x1) + (long long)b * CC * HW;
#pragma unroll
    for (int ct = 0; ct < 8; ct++)
#pragma unroll
        for (int r = 0; r < 4; r++) {
            int c = ct * 16 + 4 * g + r;
            float bias = vs ? (bo[128 + c] + bo[256 + c]) : bo[c];
            float base = xq[(long long)(128 + c) * HW + m];
            out[(((long long)(qi * 4 + b)) * CC + 128 + c) * HW + m]
                = base + acc[ct][r] + bias;
        }
}

// ---------------------------------------------------------------------------
extern "C" void kernel_launch(void* const* d_in, const int* in_sizes, int n_in,
                              void* d_out, int out_size, void* d_ws, size_t ws_size,
                              hipStream_t stream) {
    const float* x0 = (const float*)d_in[0];
    const float* x1 = (const float*)d_in[1];
    const float* x2 = (const float*)d_in[2];
    const float* Wq = (const float*)d_in[3];
    const float* bq = (const float*)d_in[4];
    const float* Wk = (const float*)d_in[5];
    const float* bk = (const float*)d_in[6];
    const float* Wv = (const float*)d_in[7];
    const float* bv = (const float*)d_in[8];
    const float* Wo = (const float*)d_in[9];
    const float* bo = (const float*)d_in[10];
    const float* dw_w = (const float*)d_in[11];
    const float* dw_b = (const float*)d_in[12];
    const float* ln_g = (const float*)d_in[13];
    const float* ln_b = (const float*)d_in[14];
    const float* pw_w = (const float*)d_in[15];
    const float* rpe = (const float*)d_in[16];
    float* out = (float*)d_out;

    // Region A: qbuf f32 (K2 w, K3 r) -> obuf f32 (K5 w, K6 r), disjoint.
    float* ws = (float*)d_ws;
    float* qbuf = ws;                                   // 6291456 f (24 MB)
    float* obuf = qbuf;                                 // alias (disjoint lifetime)
    float* posb = ws + 6291456;                         // 6144 f
    unsigned short* xT = (unsigned short*)(posb + 6144);     // 4194304 s (8 MB)
    unsigned short* qbf = xT + 4194304;                      // 12582912 s (24 MB)
    unsigned short* kbf = qbf + 12582912;                    // 393216 s
    unsigned short* vbf = kbf + 393216;                      // 393216 s
    unsigned short* tabbf = vbf + 393216;                    // 196608 s
    uint4* prmb = (uint4*)(tabbf + 196608);                  // 3072 uint4
    unsigned short* wqh = (unsigned short*)(prmb + 3072);    // 49152 s
    unsigned short* wql = wqh + 49152;
    unsigned short* woh = wql + 49152;
    unsigned short* wkh = woh + 49152;
    unsigned short* wvh = wkh + 49152;
    // total ~ 59 MB

    prep_copy<<<1048, 256, 0, stream>>>(rpe, Wq, Wo, Wk, Wv, x0, tabbf,
                                        wqh, wql, woh, wkh, wvh, out);
    conv_q<<<768, 256, 0, stream>>>(x1, x2, wqh, wql, bq, qbuf, qbf, out);
    mid_kernel<<<2240, 256, 0, stream>>>(qbuf, dw_w, dw_b, ln_g, ln_b, pw_w,
                                         x0, x1, posb, prmb, xT);
    sample_kv<<<96, 256, 0, stream>>>(xT, posb, wkh, wvh, bk, bv, kbf, vbf);
    attn_mfma<<<1536, 512, 0, stream>>>(qbf, kbf, vbf, tabbf, prmb, obuf);
    conv_wo<<<512, 256, 0, stream>>>(x1, x2, obuf, woh, bo, out);
}